// Round 3
// baseline (905.421 us; speedup 1.0000x reference)
//
#include <hip/hip_runtime.h>
#include <cstdint>

// Shapes: B=8, C=256, H=W=64 -> N=4096, d=32, groups=32 (8 ch/group)

typedef __bf16 bf16x8 __attribute__((ext_vector_type(8)));
typedef float f32x4 __attribute__((ext_vector_type(4)));
typedef float f32x16 __attribute__((ext_vector_type(16)));
typedef unsigned int u32x4 __attribute__((ext_vector_type(4)));
typedef unsigned short u16x4 __attribute__((ext_vector_type(4)));
typedef unsigned short u16x8 __attribute__((ext_vector_type(8)));

#define DEVI __device__ __forceinline__

DEVI unsigned short f2bf(float f) {
    __bf16 h = (__bf16)f;               // RNE fptrunc
    return __builtin_bit_cast(unsigned short, h);
}
DEVI float bf2f(unsigned short u) {
    unsigned int x = ((unsigned int)u) << 16;
    return __builtin_bit_cast(float, x);
}

DEVI f32x4 mfma16(bf16x8 a, bf16x8 b, f32x4 c) {
    return __builtin_amdgcn_mfma_f32_16x16x32_bf16(a, b, c, 0, 0, 0);
}
DEVI f32x16 mfma32(bf16x8 a, bf16x8 b, f32x16 c) {
    return __builtin_amdgcn_mfma_f32_32x32x16_bf16(a, b, c, 0, 0, 0);
}

// async global->LDS, 16B per lane, wave-uniform LDS base + lane*16
DEVI void glds16(const unsigned short* g, unsigned short* l) {
    const __attribute__((address_space(1))) unsigned int* gp =
        reinterpret_cast<const __attribute__((address_space(1))) unsigned int*>(
            reinterpret_cast<uintptr_t>(g));
    __attribute__((address_space(3))) unsigned int* lp =
        reinterpret_cast<__attribute__((address_space(3))) unsigned int*>(
            reinterpret_cast<uintptr_t>(l));
    __builtin_amdgcn_global_load_lds(gp, lp, 16, 0, 0);
}

// raw barrier without the compiler's vmcnt(0)-drain; manual waits only
DEVI void barrier_raw() {
    asm volatile("" ::: "memory");
    __builtin_amdgcn_s_barrier();
    asm volatile("" ::: "memory");
}
// SIMM16: vmcnt[3:0]=N, expcnt[6:4]=7, lgkmcnt[13:8]=0x3F, vmcnt[5:4]=0
DEVI void wait_vm0() { __builtin_amdgcn_s_waitcnt(0x3F70); }
DEVI void wait_vm4() { __builtin_amdgcn_s_waitcnt(0x3F74); }
DEVI void wait_vm5() { __builtin_amdgcn_s_waitcnt(0x3F75); }

// log2(e)/sqrt(32): folded into Wq so S exits QK-MFMA in exp2 domain
#define QSCALE 0.2550663133f
#define MFIX   12.0f

// ---------------- weight pack fp32 -> bf16 ----------------
__global__ __launch_bounds__(256) void k_pack(
        const float* __restrict__ wq, const float* __restrict__ wk,
        const float* __restrict__ wv, const float* __restrict__ wp,
        unsigned short* __restrict__ bqk, unsigned short* __restrict__ bv,
        unsigned short* __restrict__ bp) {
    int i = blockIdx.x * 256 + threadIdx.x;        // grid 256 -> 65536 threads
    if (i < 8192)       bqk[i] = f2bf(wq[i] * QSCALE);   // rows 0..31 = Wq (pre-scaled)
    else if (i < 16384) bqk[i] = f2bf(wk[i - 8192]);     // rows 32..63 = Wk
    bv[i] = f2bf(wv[i]);
    bp[i] = f2bf(wp[i]);
}

// ---------------- group norm -> h^T (B*N, C) bf16 ----------------
__global__ __launch_bounds__(1024) void k_gnorm(
        const float* __restrict__ x, const float* __restrict__ gw,
        const float* __restrict__ gb, unsigned short* __restrict__ ht) {
    int bg = blockIdx.x;               // 256 blocks = 8 batches * 32 groups
    int b = bg >> 5, g = bg & 31;
    const float* xb = x + ((size_t)(b * 256 + g * 8)) * 4096;  // 8 contiguous rows
    int t = threadIdx.x;
    float s1 = 0.f, s2 = 0.f;
    const f32x4* xv4 = (const f32x4*)xb;
    for (int i = t; i < 8192; i += 1024) {
        f32x4 v = xv4[i];
        #pragma unroll
        for (int j = 0; j < 4; j++) { s1 += v[j]; s2 += v[j] * v[j]; }
    }
    #pragma unroll
    for (int off = 1; off < 64; off <<= 1) {
        s1 += __shfl_xor(s1, off);
        s2 += __shfl_xor(s2, off);
    }
    __shared__ float red[34];
    int wv_ = t >> 6;
    if ((t & 63) == 0) { red[wv_ * 2] = s1; red[wv_ * 2 + 1] = s2; }
    __syncthreads();
    if (t == 0) {
        float a = 0.f, q = 0.f;
        #pragma unroll
        for (int i = 0; i < 16; i++) { a += red[i * 2]; q += red[i * 2 + 1]; }
        float mean = a * (1.f / 32768.f);
        float var = q * (1.f / 32768.f) - mean * mean;
        red[32] = mean; red[33] = rsqrtf(var + 1e-5f);
    }
    __syncthreads();
    float mean = red[32], rstd = red[33];
    float wv8[8], bv8[8];
    #pragma unroll
    for (int c = 0; c < 8; c++) { wv8[c] = gw[g * 8 + c] * rstd; bv8[c] = gb[g * 8 + c] - mean * rstd * gw[g * 8 + c]; }
    int n0 = t * 4;
    f32x4 cv[8];
    #pragma unroll
    for (int c = 0; c < 8; c++) cv[c] = *(const f32x4*)(xb + c * 4096 + n0);
    #pragma unroll
    for (int j = 0; j < 4; j++) {
        u16x8 pk;
        #pragma unroll
        for (int c = 0; c < 8; c++) pk[c] = f2bf(cv[c][j] * wv8[c] + bv8[c]);
        *(u16x8*)(&ht[((size_t)(b * 4096 + n0 + j)) * 256 + g * 8]) = pk;  // 16B store
    }
}

// ---------------- GEMM  C[M x Ncols] = A[M x 256] * Bw[Ncols x 256]^T ----------------
// EPI 0: bf16 row-major out (ldout).  EPI 1: bf16 transposed Vt[b][o][n] with
//        key-dim bit2<->bit3 swap per 16-group (PV A-frag permutation).
// EPI 2: fp32 transposed + residual: out[b][o][n] = x + gamma*acc.
// Grid is the original 2D form (x: m-panels, y: n-blocks). Round-1/2 evidence:
// per-XCD A-slice (2 MB) is L2-resident across y-slices already; a 1D
// XCD-affine swizzle measured ~6 us SLOWER. Keep 2D.
template <int EPI>
__global__ __launch_bounds__(256) void k_gemm(
        const unsigned short* __restrict__ A, const unsigned short* __restrict__ Bw,
        void* __restrict__ outp, const float* __restrict__ xres,
        const float* __restrict__ gamma, int ldout) {
    __shared__ unsigned short lA[128 * 72];
    __shared__ unsigned short lB[64 * 72];
    int t = threadIdx.x;
    int m0 = blockIdx.x * 128, n0 = blockIdx.y * 64;
    int w = t >> 6, lane = t & 63, l15 = lane & 15, quad = lane >> 4;
    f32x4 z4 = {0.f, 0.f, 0.f, 0.f};
    f32x4 acc[2][4];
    #pragma unroll
    for (int i = 0; i < 2; i++)
        #pragma unroll
        for (int j = 0; j < 4; j++) acc[i][j] = z4;

    for (int kb = 0; kb < 4; kb++) {
        #pragma unroll
        for (int i = 0; i < 4; i++) {
            int ch = i * 256 + t;
            int row = ch >> 3, col = (ch & 7) * 8;
            u32x4 v = *(const u32x4*)(A + (size_t)(m0 + row) * 256 + kb * 64 + col);
            *(u32x4*)(&lA[row * 72 + col]) = v;
        }
        #pragma unroll
        for (int i = 0; i < 2; i++) {
            int ch = i * 256 + t;
            int row = ch >> 3, col = (ch & 7) * 8;
            u32x4 v = *(const u32x4*)(Bw + (size_t)(n0 + row) * 256 + kb * 64 + col);
            *(u32x4*)(&lB[row * 72 + col]) = v;
        }
        __syncthreads();
        #pragma unroll
        for (int ks = 0; ks < 2; ks++) {
            bf16x8 af[2], bfr[4];
            #pragma unroll
            for (int fr = 0; fr < 2; fr++)
                af[fr] = *(const bf16x8*)(&lA[(w * 32 + fr * 16 + l15) * 72 + ks * 32 + quad * 8]);
            #pragma unroll
            for (int fn = 0; fn < 4; fn++)
                bfr[fn] = *(const bf16x8*)(&lB[(fn * 16 + l15) * 72 + ks * 32 + quad * 8]);
            #pragma unroll
            for (int fr = 0; fr < 2; fr++)
                #pragma unroll
                for (int fn = 0; fn < 4; fn++)
                    acc[fr][fn] = mfma16(af[fr], bfr[fn], acc[fr][fn]);
        }
        __syncthreads();
    }

    if (EPI == 0) {
        unsigned short* out = (unsigned short*)outp;
        #pragma unroll
        for (int fr = 0; fr < 2; fr++)
            #pragma unroll
            for (int fn = 0; fn < 4; fn++)
                #pragma unroll
                for (int r = 0; r < 4; r++) {
                    int m = m0 + w * 32 + fr * 16 + quad * 4 + r;
                    int n = n0 + fn * 16 + l15;
                    out[(size_t)m * ldout + n] = f2bf(acc[fr][fn][r]);
                }
    } else if (EPI == 1) {
        unsigned short* out = (unsigned short*)outp;
        int b = m0 >> 12, nb = (m0 & 4095) + w * 32;
        int swq = ((quad & 1) << 1) | (quad >> 1);   // bit2<->bit3 swap of n within 16
        #pragma unroll
        for (int fr = 0; fr < 2; fr++)
            #pragma unroll
            for (int fn = 0; fn < 4; fn++) {
                int o = n0 + fn * 16 + l15;
                int n = nb + fr * 16 + swq * 4;
                u16x4 pk;
                #pragma unroll
                for (int r = 0; r < 4; r++) pk[r] = f2bf(acc[fr][fn][r]);
                *(u16x4*)(&out[(((size_t)(b * 256 + o)) << 12) + n]) = pk;
            }
    } else {
        float* out = (float*)outp;
        float gm = gamma[0];
        int b = m0 >> 12, nb = (m0 & 4095) + w * 32;
        #pragma unroll
        for (int fr = 0; fr < 2; fr++)
            #pragma unroll
            for (int fn = 0; fn < 4; fn++) {
                int o = n0 + fn * 16 + l15;
                int n = nb + fr * 16 + quad * 4;
                size_t base = (((size_t)(b * 256 + o)) << 12) + n;
                f32x4 xv = *(const f32x4*)(xres + base);
                f32x4 ov;
                #pragma unroll
                for (int r = 0; r < 4; r++) ov[r] = xv[r] + gm * acc[fr][fn][r];
                *(f32x4*)(out + base) = ov;
            }
    }
}

// ---------------- flash attention: 32x32 MFMA, cross-tile pipeline ----------------
// QK: (B*N, 64) bf16 (q cols 0..31 pre-scaled, k cols 32..63).
// Vt: (B, 256, N) bf16, key-dim sigma-permuted (bit2<->bit3 per 16-group).
// Grid 512 = 8 b x 32 qblk(128q) x 2 oh(128 o-chans). 4 waves = 2 qh x 2 kh.
//
// Round-3 structure (register-neutral version of the round-1 pipeline):
//  - Q fragments moved to LDS (frees the 16 persistent qb VGPRs; row-padded
//    stride 36 shorts -> 2-way bank conflict = free). barrier_raw's memory
//    clobber each body prevents LICM from hoisting the Q reads back to regs.
//  - paA/paB double-buffered P fragments (+16 VGPRs) carried across the
//    barrier: body t computes QK+exp(t) AND PV(t-1); both depend only on
//    already-staged tiles, so the compiler interleaves exp2/cvt VALU under
//    the 16 PV MFMAs. Net VGPR delta ~0 (round-1 spilled at +30).
//  - 3 K-buffers (12KB) + 3 V-buffers (48KB), counted vmcnt(5): each body's
//    5 loads (1 K + 4 V) stay in flight 2 full bodies; ONE barrier per body.
//    Within a body staged slots != read slots (mod 3); cross-body reuse is
//    protected by the top-of-body barrier.
//  - Spill tripwire: if VGPR busts, WRITE_SIZE explodes (round-1 signature).
__global__ __launch_bounds__(256, 2) void k_flash(
        const unsigned short* __restrict__ QK, const unsigned short* __restrict__ Vt,
        unsigned short* __restrict__ Oa) {
    // layout: Q 0..9215 | K0 9216 K1 13312 K2 17408 | V0 21504 V1 37888 V2 54272
    __shared__ __align__(16) char smem[70656];
    int id = blockIdx.x;
    int b = id & 7;                    // batch <-> XCD affinity
    int r3 = id >> 3;
    int oh = r3 & 1, qblk = r3 >> 1;   // o-half, q-block(128)
    int t = threadIdx.x, w = t >> 6, ln = t & 63;
    int l31 = ln & 31, h = ln >> 5;
    int qh = w >> 1, kh = w & 1;

    unsigned short* const sQ  = (unsigned short*)smem;
    unsigned short* const Kb0 = (unsigned short*)(smem + 9216);
    unsigned short* const Kb1 = (unsigned short*)(smem + 13312);
    unsigned short* const Kb2 = (unsigned short*)(smem + 17408);
    unsigned short* const Vb0 = (unsigned short*)(smem + 21504);
    unsigned short* const Vb1 = (unsigned short*)(smem + 37888);
    unsigned short* const Vb2 = (unsigned short*)(smem + 54272);
    // per-wave staging destinations
    unsigned short* const sKs0 = Kb0 + w * 512;
    unsigned short* const sKs1 = Kb1 + w * 512;
    unsigned short* const sKs2 = Kb2 + w * 512;
    unsigned short* const sVs0 = Vb0 + w * 2048;
    unsigned short* const sVs1 = Vb1 + w * 2048;
    unsigned short* const sVs2 = Vb2 + w * 2048;

    // staging: K tile (wave w stages keys w*16..+16), chunk-swizzled for A-frag reads
    int cgK = (ln & 3) ^ ((ln >> 2) & 3) ^ ((ln >> 4) & 3);
    const unsigned short* gK = QK + ((size_t)(b * 4096 + w * 16 + (ln >> 2))) * 64 + 32 + cgK * 8;
    // V half-tile: wave w stages o-rows oh*128 + w*32..+32, chunk-swizzled
    int vc8 = (ln & 7) ^ ((ln >> 3) & 7);
    const unsigned short* gV = Vt + (((size_t)(b * 256 + oh * 128 + w * 32 + (ln >> 3))) << 12) + vc8 * 8;

    // ---- prolog: Q -> LDS (padded stride 36), K(0),K(1),V(0) staged ----
    {
        int row = t >> 1, hf = t & 1;  // 256 threads -> 128 rows x 2 halves
        const unsigned short* qg = QK + ((size_t)(b * 4096 + qblk * 128 + row)) * 64 + hf * 16;
        u32x4 a0 = *(const u32x4*)qg;
        u32x4 a1 = *(const u32x4*)(qg + 8);
        *(u32x4*)(&sQ[row * 36 + hf * 16]) = a0;
        *(u32x4*)(&sQ[row * 36 + hf * 16 + 8]) = a1;
    }
    glds16(gK + (size_t)0 * 4096, sKs0);
    glds16(gK + (size_t)1 * 4096, sKs1);
    #pragma unroll
    for (int j = 0; j < 4; j++) glds16(gV + ((size_t)j * 8 << 12) + 0 * 64, sVs0 + j * 512);

    f32x16 z16;
    #pragma unroll
    for (int i = 0; i < 16; i++) z16[i] = 0.f;
    f32x16 minit;
    #pragma unroll
    for (int i = 0; i < 16; i++) minit[i] = -MFIX;
    f32x16 Oacc[2][4];
    #pragma unroll
    for (int qt2 = 0; qt2 < 2; qt2++)
        #pragma unroll
        for (int i = 0; i < 4; i++) Oacc[qt2][i] = z16;
    float lsum[2] = {0.f, 0.f};        // per-lane partial rowsum (q=l31, this h's keys)

    // loop-invariant LDS read offsets
    int gl = (l31 & 3) ^ ((l31 >> 2) & 3);
    const int koff0 = (kh * 32 + l31) * 32 + ((0 + h) ^ gl) * 8;
    const int koff1 = (kh * 32 + l31) * 32 + ((2 + h) ^ gl) * 8;
    const unsigned short* const kp0_0 = Kb0 + koff0;
    const unsigned short* const kp1_0 = Kb0 + koff1;
    const unsigned short* const kp0_1 = Kb1 + koff0;
    const unsigned short* const kp1_1 = Kb1 + koff1;
    const unsigned short* const kp0_2 = Kb2 + koff0;
    const unsigned short* const kp1_2 = Kb2 + koff1;
    const int slotA = ((kh * 4 + 0 * 2 + h) ^ (ln & 7)) * 8;
    const int slotB = ((kh * 4 + 1 * 2 + h) ^ (ln & 7)) * 8;
    // Q frag base: row = qh*64 + qt2*32 + l31, cols h*8.. ; qt2 offset = 32*36 shorts
    const unsigned short* const qbase = sQ + (qh * 64 + l31) * 36 + h * 8;

    auto stageK = [&](int kn, unsigned short* dst) {
        glds16(gK + (size_t)kn * 4096, dst);
    };
    auto stageV = [&](int kn, unsigned short* dst) {
        #pragma unroll
        for (int j = 0; j < 4; j++)
            glds16(gV + ((size_t)j * 8 << 12) + kn * 64, dst + j * 512);
    };

    // QK MFMA + exp2 + rowsum for tile t -> pa (producer); Q frags from LDS
    auto qkexp = [&](const unsigned short* kp0, const unsigned short* kp1,
                     bf16x8 (&pa)[2][2]) {
        bf16x8 kf0 = *(const bf16x8*)kp0;
        bf16x8 kf1 = *(const bf16x8*)kp1;
        #pragma unroll
        for (int qt2 = 0; qt2 < 2; qt2++) {
            bf16x8 qv0 = *(const bf16x8*)(qbase + qt2 * 1152);
            bf16x8 qv1 = *(const bf16x8*)(qbase + qt2 * 1152 + 16);
            f32x16 St = mfma32(kf0, qv0, minit);
            St = mfma32(kf1, qv1, St);
            u16x8 p0u, p1u;
            float s = 0.f;
            #pragma unroll
            for (int j = 0; j < 8; j++) {
                float e0 = __builtin_amdgcn_exp2f(St[j]);
                float e1 = __builtin_amdgcn_exp2f(St[8 + j]);
                s += e0 + e1;                       // rowsum in VALU (lane=q, regs=keys)
                p0u[j] = f2bf(e0);
                p1u[j] = f2bf(e1);
            }
            lsum[qt2] += s;
            pa[qt2][0] = __builtin_bit_cast(bf16x8, p0u);
            pa[qt2][1] = __builtin_bit_cast(bf16x8, p1u);
        }
    };

    // PV MFMAs for the previous tile (consumer; independent of qkexp's VALU)
    auto pv = [&](const unsigned short* bV, bf16x8 (&pa)[2][2]) {
        __builtin_amdgcn_s_setprio(1);
        #pragma unroll
        for (int nt = 0; nt < 4; nt++) {
            bf16x8 vf = *(const bf16x8*)(bV + (nt * 32 + l31) * 64 + slotA);
            Oacc[0][nt] = mfma32(pa[0][0], vf, Oacc[0][nt]);
            Oacc[1][nt] = mfma32(pa[1][0], vf, Oacc[1][nt]);
        }
        #pragma unroll
        for (int nt = 0; nt < 4; nt++) {
            bf16x8 vf = *(const bf16x8*)(bV + (nt * 32 + l31) * 64 + slotB);
            Oacc[0][nt] = mfma32(pa[0][1], vf, Oacc[0][nt]);
            Oacc[1][nt] = mfma32(pa[1][1], vf, Oacc[1][nt]);
        }
        __builtin_amdgcn_s_setprio(0);
    };

    bf16x8 paA[2][2], paB[2][2];

    __syncthreads();                    // drain Q ds_writes + prolog glds (full drain, once)

    // body 0 (t=0): stage K(2),V(1); qkexp(0)->paA; no pv
    stageK(2, sKs2);
    stageV(1, sVs1);
    qkexp(kp0_0, kp1_0, paA);
    // body 1 (t=1): stage K(3)->K0, V(2)->V2; qkexp(1)->paB; pv(0)
    wait_vm5(); barrier_raw();
    stageK(3, sKs0);
    stageV(2, sVs2);
    qkexp(kp0_1, kp1_1, paB);
    pv(Vb0, paA);

    // main: t = 2..61, 6-unrolled (3-buffer rotation x 2 pa sets)
    for (int kt = 2; kt < 62; kt += 6) {
        // t=kt+0 (t%3=2): Kcur2 Kstage1, Vpv1 Vstage0, paA<-qk, pv paB
        wait_vm5(); barrier_raw();
        stageK(kt + 2, sKs1);
        stageV(kt + 1, sVs0);
        qkexp(kp0_2, kp1_2, paA);
        pv(Vb1, paB);
        // t=kt+1 (t%3=0): Kcur0 Kstage2, Vpv2 Vstage1, paB, pv paA
        wait_vm5(); barrier_raw();
        stageK(kt + 3, sKs2);
        stageV(kt + 2, sVs1);
        qkexp(kp0_0, kp1_0, paB);
        pv(Vb2, paA);
        // t=kt+2 (t%3=1): Kcur1 Kstage0, Vpv0 Vstage2, paA, pv paB
        wait_vm5(); barrier_raw();
        stageK(kt + 4, sKs0);
        stageV(kt + 3, sVs2);
        qkexp(kp0_1, kp1_1, paA);
        pv(Vb0, paB);
        // t=kt+3 (t%3=2): Kcur2 Kstage1, Vpv1 Vstage0, paB, pv paA
        wait_vm5(); barrier_raw();
        stageK(kt + 5, sKs1);
        stageV(kt + 4, sVs0);
        qkexp(kp0_2, kp1_2, paB);
        pv(Vb1, paA);
        // t=kt+4 (t%3=0): Kcur0 Kstage2, Vpv2 Vstage1, paA, pv paB
        wait_vm5(); barrier_raw();
        stageK(kt + 6, sKs2);
        stageV(kt + 5, sVs1);
        qkexp(kp0_0, kp1_0, paA);
        pv(Vb2, paB);
        // t=kt+5 (t%3=1): Kcur1 Kstage0, Vpv0 Vstage2, paB, pv paA
        wait_vm5(); barrier_raw();
        stageK(kt + 7, sKs0);
        stageV(kt + 6, sVs2);
        qkexp(kp0_1, kp1_1, paB);
        pv(Vb0, paA);
    }
    // body 62 (t=62, t%3=2): stage V(63)->V0 only; qkexp(62)->paA; pv(61)=V1,paB
    wait_vm5(); barrier_raw();
    stageV(63, sVs0);
    qkexp(kp0_2, kp1_2, paA);
    pv(Vb1, paB);
    // body 63 (t=63, t%3=0): qkexp(63)->paB; pv(62)=V2,paA
    wait_vm4(); barrier_raw();          // drain K(63)+V(62); V(63)'s 4 stay in flight
    qkexp(kp0_0, kp1_0, paB);
    pv(Vb2, paA);
    // drain: pv(63)=V0,paB
    wait_vm0(); barrier_raw();
    pv(Vb0, paB);

    // finish rowsums: combine the two h-halves (lane l31 and l31+32 hold
    // complementary key subsets for the same q)
    #pragma unroll
    for (int qt2 = 0; qt2 < 2; qt2++) lsum[qt2] += __shfl_xor(lsum[qt2], 32);
    __syncthreads();                    // all LDS reads done before smem reuse

    // ---- epilogue via smem reuse ----
    float* sf = (float*)smem;
    // lsum publish: [8192 + qh*64 + qt2*32 + q] (kh1), [8320 + ...] (kh0)
    int lbase = (kh ? 8192 : 8320) + qh * 64 + l31;
    sf[lbase] = lsum[0];
    sf[lbase + 32] = lsum[1];
    if (kh == 1) {                      // publish O partials (bf16)
        #pragma unroll
        for (int qt2 = 0; qt2 < 2; qt2++)
            #pragma unroll
            for (int nt = 0; nt < 4; nt++)
                #pragma unroll
                for (int rg = 0; rg < 2; rg++) {
                    u16x8 pk;
                    #pragma unroll
                    for (int j = 0; j < 8; j++) pk[j] = f2bf(Oacc[qt2][nt][rg * 8 + j]);
                    *(u16x8*)(smem + qh * 16384 + qt2 * 8192 + nt * 2048 + rg * 1024 + ln * 16) = pk;
                }
    }
    __syncthreads();
    if (kh == 0) {                      // reduce + normalize + store
        #pragma unroll
        for (int qt2 = 0; qt2 < 2; qt2++) {
            float rl[16];
            #pragma unroll
            for (int r = 0; r < 16; r++) {
                int row = (r & 3) + 8 * (r >> 2) + 4 * h;
                float l = sf[8192 + qh * 64 + qt2 * 32 + row] +
                          sf[8320 + qh * 64 + qt2 * 32 + row];
                rl[r] = 1.f / l;
            }
            size_t rb = (size_t)(b * 4096 + qblk * 128 + qh * 64 + qt2 * 32);
            #pragma unroll
            for (int nt = 0; nt < 4; nt++)
                #pragma unroll
                for (int rg = 0; rg < 2; rg++) {
                    u16x8 pk = *(const u16x8*)(smem + qh * 16384 + qt2 * 8192 + nt * 2048 + rg * 1024 + ln * 16);
                    #pragma unroll
                    for (int j = 0; j < 8; j++) {
                        int r = rg * 8 + j;
                        float val = (Oacc[qt2][nt][r] + bf2f(pk[j])) * rl[r];
                        int row = (r & 3) + 8 * (r >> 2) + 4 * h;
                        Oa[(rb + row) * 256 + oh * 128 + nt * 32 + l31] = f2bf(val);
                    }
                }
        }
    }
}

// ---------------- launch ----------------
extern "C" void kernel_launch(void* const* d_in, const int* in_sizes, int n_in,
                              void* d_out, int out_size, void* d_ws, size_t ws_size,
                              hipStream_t stream) {
    const float* x  = (const float*)d_in[0];
    const float* nw = (const float*)d_in[1];
    const float* nb = (const float*)d_in[2];
    const float* wq = (const float*)d_in[3];
    const float* wk = (const float*)d_in[4];
    const float* wv = (const float*)d_in[5];
    const float* wp = (const float*)d_in[6];
    const float* gm = (const float*)d_in[7];

    char* p = (char*)d_ws;
    unsigned short* ht  = (unsigned short*)p; p += (size_t)32768 * 256 * 2;  // 16 MB
    unsigned short* qk  = (unsigned short*)p; p += (size_t)32768 * 64 * 2;   // 4 MB
    unsigned short* vt  = (unsigned short*)p; p += (size_t)8 * 256 * 4096 * 2; // 16 MB
    unsigned short* oa  = (unsigned short*)p; p += (size_t)32768 * 256 * 2;  // 16 MB
    unsigned short* bqk = (unsigned short*)p; p += 64 * 256 * 2;
    unsigned short* bv  = (unsigned short*)p; p += 256 * 256 * 2;
    unsigned short* bp  = (unsigned short*)p; p += 256 * 256 * 2;

    k_pack<<<dim3(256), dim3(256), 0, stream>>>(wq, wk, wv, wp, bqk, bv, bp);
    k_gnorm<<<dim3(256), dim3(1024), 0, stream>>>(x, nw, nb, ht);
    k_gemm<0><<<dim3(256, 1), dim3(256), 0, stream>>>(ht, bqk, (void*)qk, nullptr, nullptr, 64);
    k_gemm<1><<<dim3(256, 4), dim3(256), 0, stream>>>(ht, bv, (void*)vt, nullptr, nullptr, 0);
    k_flash<<<dim3(512), dim3(256), 0, stream>>>(qk, vt, oa);
    k_gemm<2><<<dim3(256, 4), dim3(256), 0, stream>>>(oa, bp, d_out, x, gm, 0);
}

// Round 4
// 268.957 us; speedup vs baseline: 3.3664x; 3.3664x over previous
//
#include <hip/hip_runtime.h>
#include <cstdint>

// Shapes: B=8, C=256, H=W=64 -> N=4096, d=32, groups=32 (8 ch/group)

typedef __bf16 bf16x8 __attribute__((ext_vector_type(8)));
typedef float f32x4 __attribute__((ext_vector_type(4)));
typedef float f32x16 __attribute__((ext_vector_type(16)));
typedef unsigned int u32x4 __attribute__((ext_vector_type(4)));
typedef unsigned short u16x4 __attribute__((ext_vector_type(4)));
typedef unsigned short u16x8 __attribute__((ext_vector_type(8)));

#define DEVI __device__ __forceinline__

DEVI unsigned short f2bf(float f) {
    __bf16 h = (__bf16)f;               // RNE fptrunc
    return __builtin_bit_cast(unsigned short, h);
}
DEVI float bf2f(unsigned short u) {
    unsigned int x = ((unsigned int)u) << 16;
    return __builtin_bit_cast(float, x);
}

DEVI f32x4 mfma16(bf16x8 a, bf16x8 b, f32x4 c) {
    return __builtin_amdgcn_mfma_f32_16x16x32_bf16(a, b, c, 0, 0, 0);
}
DEVI f32x16 mfma32(bf16x8 a, bf16x8 b, f32x16 c) {
    return __builtin_amdgcn_mfma_f32_32x32x16_bf16(a, b, c, 0, 0, 0);
}

// async global->LDS, 16B per lane, wave-uniform LDS base + lane*16
DEVI void glds16(const unsigned short* g, unsigned short* l) {
    const __attribute__((address_space(1))) unsigned int* gp =
        reinterpret_cast<const __attribute__((address_space(1))) unsigned int*>(
            reinterpret_cast<uintptr_t>(g));
    __attribute__((address_space(3))) unsigned int* lp =
        reinterpret_cast<__attribute__((address_space(3))) unsigned int*>(
            reinterpret_cast<uintptr_t>(l));
    __builtin_amdgcn_global_load_lds(gp, lp, 16, 0, 0);
}

// raw barrier without the compiler's vmcnt(0)-drain; manual waits only
DEVI void barrier_raw() {
    asm volatile("" ::: "memory");
    __builtin_amdgcn_s_barrier();
    asm volatile("" ::: "memory");
}
DEVI void wait_vm0() {
    // SIMM16: vmcnt[3:0]=0, expcnt[6:4]=7, lgkmcnt[13:8]=0x3F, vmcnt[5:4]=0
    __builtin_amdgcn_s_waitcnt(0x3F70);
}

// log2(e)/sqrt(32): folded into Wq so S exits QK-MFMA in exp2 domain
#define QSCALE 0.2550663133f
#define MFIX   12.0f

// ---------------- weight pack fp32 -> bf16 ----------------
__global__ __launch_bounds__(256) void k_pack(
        const float* __restrict__ wq, const float* __restrict__ wk,
        const float* __restrict__ wv, const float* __restrict__ wp,
        unsigned short* __restrict__ bqk, unsigned short* __restrict__ bv,
        unsigned short* __restrict__ bp) {
    int i = blockIdx.x * 256 + threadIdx.x;        // grid 256 -> 65536 threads
    if (i < 8192)       bqk[i] = f2bf(wq[i] * QSCALE);   // rows 0..31 = Wq (pre-scaled)
    else if (i < 16384) bqk[i] = f2bf(wk[i - 8192]);     // rows 32..63 = Wk
    bv[i] = f2bf(wv[i]);
    bp[i] = f2bf(wp[i]);
}

// ---------------- group norm -> h^T (B*N, C) bf16 ----------------
__global__ __launch_bounds__(1024) void k_gnorm(
        const float* __restrict__ x, const float* __restrict__ gw,
        const float* __restrict__ gb, unsigned short* __restrict__ ht) {
    int bg = blockIdx.x;               // 256 blocks = 8 batches * 32 groups
    int b = bg >> 5, g = bg & 31;
    const float* xb = x + ((size_t)(b * 256 + g * 8)) * 4096;  // 8 contiguous rows
    int t = threadIdx.x;
    float s1 = 0.f, s2 = 0.f;
    const f32x4* xv4 = (const f32x4*)xb;
    for (int i = t; i < 8192; i += 1024) {
        f32x4 v = xv4[i];
        #pragma unroll
        for (int j = 0; j < 4; j++) { s1 += v[j]; s2 += v[j] * v[j]; }
    }
    #pragma unroll
    for (int off = 1; off < 64; off <<= 1) {
        s1 += __shfl_xor(s1, off);
        s2 += __shfl_xor(s2, off);
    }
    __shared__ float red[34];
    int wv_ = t >> 6;
    if ((t & 63) == 0) { red[wv_ * 2] = s1; red[wv_ * 2 + 1] = s2; }
    __syncthreads();
    if (t == 0) {
        float a = 0.f, q = 0.f;
        #pragma unroll
        for (int i = 0; i < 16; i++) { a += red[i * 2]; q += red[i * 2 + 1]; }
        float mean = a * (1.f / 32768.f);
        float var = q * (1.f / 32768.f) - mean * mean;
        red[32] = mean; red[33] = rsqrtf(var + 1e-5f);
    }
    __syncthreads();
    float mean = red[32], rstd = red[33];
    float wv8[8], bv8[8];
    #pragma unroll
    for (int c = 0; c < 8; c++) { wv8[c] = gw[g * 8 + c] * rstd; bv8[c] = gb[g * 8 + c] - mean * rstd * gw[g * 8 + c]; }
    int n0 = t * 4;
    f32x4 cv[8];
    #pragma unroll
    for (int c = 0; c < 8; c++) cv[c] = *(const f32x4*)(xb + c * 4096 + n0);
    #pragma unroll
    for (int j = 0; j < 4; j++) {
        u16x8 pk;
        #pragma unroll
        for (int c = 0; c < 8; c++) pk[c] = f2bf(cv[c][j] * wv8[c] + bv8[c]);
        *(u16x8*)(&ht[((size_t)(b * 4096 + n0 + j)) * 256 + g * 8]) = pk;  // 16B store
    }
}

// ---------------- GEMM  C[M x Ncols] = A[M x 256] * Bw[Ncols x 256]^T ----------------
// EPI 0: bf16 row-major out (ldout).  EPI 1: bf16 transposed Vt[b][o][n] with
//        key-dim bit2<->bit3 swap per 16-group (PV A-frag permutation).
// EPI 2: fp32 transposed + residual: out[b][o][n] = x + gamma*acc.
// EPI 3: merged QK+V projection — y==0: EPI0 path (Bw -> outp, ldout);
//        y>=1: EPI1 path (Bw2 -> outp2, n0=(y-1)*64). Saves one full read of A
//        (16 MB) and one kernel launch vs separate <0>/<1> dispatches.
// Grid is the 2D form (x: m-panels, y: n-blocks). Round-1/2 evidence: per-XCD
// A-slice is L2-resident across y-slices already; 1D XCD swizzle was ~6us SLOWER.
template <int EPI>
__global__ __launch_bounds__(256) void k_gemm(
        const unsigned short* __restrict__ A, const unsigned short* __restrict__ Bw,
        void* __restrict__ outp, const float* __restrict__ xres,
        const float* __restrict__ gamma, int ldout,
        const unsigned short* __restrict__ Bw2, void* __restrict__ outp2) {
    __shared__ unsigned short lA[128 * 72];
    __shared__ unsigned short lB[64 * 72];
    int t = threadIdx.x;
    int m0 = blockIdx.x * 128, n0 = blockIdx.y * 64;
    const unsigned short* Bsrc = Bw;
    if (EPI == 3) {
        if (blockIdx.y == 0) { n0 = 0; }
        else { Bsrc = Bw2; n0 = (blockIdx.y - 1) * 64; }
    }
    int w = t >> 6, lane = t & 63, l15 = lane & 15, quad = lane >> 4;
    f32x4 z4 = {0.f, 0.f, 0.f, 0.f};
    f32x4 acc[2][4];
    #pragma unroll
    for (int i = 0; i < 2; i++)
        #pragma unroll
        for (int j = 0; j < 4; j++) acc[i][j] = z4;

    for (int kb = 0; kb < 4; kb++) {
        #pragma unroll
        for (int i = 0; i < 4; i++) {
            int ch = i * 256 + t;
            int row = ch >> 3, col = (ch & 7) * 8;
            u32x4 v = *(const u32x4*)(A + (size_t)(m0 + row) * 256 + kb * 64 + col);
            *(u32x4*)(&lA[row * 72 + col]) = v;
        }
        #pragma unroll
        for (int i = 0; i < 2; i++) {
            int ch = i * 256 + t;
            int row = ch >> 3, col = (ch & 7) * 8;
            u32x4 v = *(const u32x4*)(Bsrc + (size_t)(n0 + row) * 256 + kb * 64 + col);
            *(u32x4*)(&lB[row * 72 + col]) = v;
        }
        __syncthreads();
        #pragma unroll
        for (int ks = 0; ks < 2; ks++) {
            bf16x8 af[2], bfr[4];
            #pragma unroll
            for (int fr = 0; fr < 2; fr++)
                af[fr] = *(const bf16x8*)(&lA[(w * 32 + fr * 16 + l15) * 72 + ks * 32 + quad * 8]);
            #pragma unroll
            for (int fn = 0; fn < 4; fn++)
                bfr[fn] = *(const bf16x8*)(&lB[(fn * 16 + l15) * 72 + ks * 32 + quad * 8]);
            #pragma unroll
            for (int fr = 0; fr < 2; fr++)
                #pragma unroll
                for (int fn = 0; fn < 4; fn++)
                    acc[fr][fn] = mfma16(af[fr], bfr[fn], acc[fr][fn]);
        }
        __syncthreads();
    }

    bool epi0 = (EPI == 0) || (EPI == 3 && blockIdx.y == 0);
    bool epi1 = (EPI == 1) || (EPI == 3 && blockIdx.y != 0);
    if (epi0) {
        unsigned short* out = (unsigned short*)outp;
        #pragma unroll
        for (int fr = 0; fr < 2; fr++)
            #pragma unroll
            for (int fn = 0; fn < 4; fn++)
                #pragma unroll
                for (int r = 0; r < 4; r++) {
                    int m = m0 + w * 32 + fr * 16 + quad * 4 + r;
                    int n = n0 + fn * 16 + l15;
                    out[(size_t)m * ldout + n] = f2bf(acc[fr][fn][r]);
                }
    } else if (epi1) {
        unsigned short* out = (unsigned short*)((EPI == 3) ? outp2 : outp);
        int b = m0 >> 12, nb = (m0 & 4095) + w * 32;
        int swq = ((quad & 1) << 1) | (quad >> 1);   // bit2<->bit3 swap of n within 16
        #pragma unroll
        for (int fr = 0; fr < 2; fr++)
            #pragma unroll
            for (int fn = 0; fn < 4; fn++) {
                int o = n0 + fn * 16 + l15;
                int n = nb + fr * 16 + swq * 4;
                u16x4 pk;
                #pragma unroll
                for (int r = 0; r < 4; r++) pk[r] = f2bf(acc[fr][fn][r]);
                *(u16x4*)(&out[(((size_t)(b * 256 + o)) << 12) + n]) = pk;
            }
    } else {
        float* out = (float*)outp;
        float gm = gamma[0];
        int b = m0 >> 12, nb = (m0 & 4095) + w * 32;
        #pragma unroll
        for (int fr = 0; fr < 2; fr++)
            #pragma unroll
            for (int fn = 0; fn < 4; fn++) {
                int o = n0 + fn * 16 + l15;
                int n = nb + fr * 16 + quad * 4;
                size_t base = (((size_t)(b * 256 + o)) << 12) + n;
                f32x4 xv = *(const f32x4*)(xres + base);
                f32x4 ov;
                #pragma unroll
                for (int r = 0; r < 4; r++) ov[r] = xv[r] + gm * acc[fr][fn][r];
                *(f32x4*)(out + base) = ov;
            }
    }
}

// ---------------- flash attention: 32x32 MFMA, dbuf, q x2 reg-block, o-split,
//                  VALU rowsum, 2 blocks/CU, within-tile MFMA/VALU pipeline ----------------
// QK: (B*N, 64) bf16 (q cols 0..31 pre-scaled, k cols 32..63).
// Vt: (B, 256, N) bf16, key-dim sigma-permuted (bit2<->bit3 per 16-group).
// Grid 512 = 8 b x 32 qblk(128q) x 2 oh(128 o-chans). 4 waves = 2 qh x 2 kh.
//
// Register budget (rounds 1+3 post-mortem, CONFIRMED TWICE): 256 VGPR/wave cap
// (Oacc 128 acc + 128 arch) has ZERO headroom. Any P-fragment carried across a
// barrier (+16 peak) spills -> ~2 GB scratch traffic. Do not.
//
// Within-tile pipeline (this round, no cross-barrier carry): issue all 4 QK
// MFMAs (St0,St1), exp(St0)->pa0, then interleave exp(St1) BETWEEN the 8 PV
// MFMAs of q-tile 0 (mutually independent; wave issue is in-order so the
// interleave must be in program order), then PV of q-tile 1. exp1's ~250 VALU
// cycles issue in the shadow of PV0's matrix-pipe occupancy. Costs 8 duplicate
// ds_read_b128 (vf no longer shared across qt2) — cheap vs the serial chain.
__global__ __launch_bounds__(256, 2) void k_flash(
        const unsigned short* __restrict__ QK, const unsigned short* __restrict__ Vt,
        unsigned short* __restrict__ Oa) {
    __shared__ __align__(16) char smem[40960];   // dbuf 2 x (4KB K + 16KB V); epilogue reuse
    int id = blockIdx.x;
    int b = id & 7;                    // batch <-> XCD affinity
    int r3 = id >> 3;
    int oh = r3 & 1, qblk = r3 >> 1;   // o-half, q-block(128)
    int t = threadIdx.x, w = t >> 6, ln = t & 63;
    int l31 = ln & 31, h = ln >> 5;
    int qh = w >> 1, kh = w & 1;
    int q0 = qblk * 128 + qh * 64;     // this wave's 64-q range (2 tiles of 32)

    // persistent Q B-frags: B[k=d][n=q]; lane: q=l31, d = s*16 + h*8 + j
    bf16x8 qb0[2], qb1[2];
    #pragma unroll
    for (int qt2 = 0; qt2 < 2; qt2++) {
        const unsigned short* qrow = QK + ((size_t)(b * 4096 + q0 + qt2 * 32 + l31)) * 64;
        qb0[qt2] = *(const bf16x8*)(qrow + h * 8);
        qb1[qt2] = *(const bf16x8*)(qrow + 16 + h * 8);
    }

    // staging: K tile (wave w stages keys w*16..+16), chunk-swizzled for A-frag reads
    int cgK = (ln & 3) ^ ((ln >> 2) & 3) ^ ((ln >> 4) & 3);
    const unsigned short* gK = QK + ((size_t)(b * 4096 + w * 16 + (ln >> 2))) * 64 + 32 + cgK * 8;
    // V half-tile: wave w stages o-rows oh*128 + w*32..+32, chunk-swizzled
    int vc8 = (ln & 7) ^ ((ln >> 3) & 7);
    const unsigned short* gV = Vt + (((size_t)(b * 256 + oh * 128 + w * 32 + (ln >> 3))) << 12) + vc8 * 8;

    // double buffers: K 4KB + V 16KB each
    unsigned short* lK0 = (unsigned short*)smem;
    unsigned short* lV0 = (unsigned short*)(smem + 4096);
    unsigned short* lK1 = (unsigned short*)(smem + 20480);
    unsigned short* lV1 = (unsigned short*)(smem + 24576);
    unsigned short* sK0 = lK0 + w * 512;
    unsigned short* sV0 = lV0 + w * 2048;
    unsigned short* sK1 = lK1 + w * 512;
    unsigned short* sV1 = lV1 + w * 2048;

    f32x16 z16;
    #pragma unroll
    for (int i = 0; i < 16; i++) z16[i] = 0.f;
    f32x16 minit;
    #pragma unroll
    for (int i = 0; i < 16; i++) minit[i] = -MFIX;
    f32x16 Oacc[2][4];
    #pragma unroll
    for (int qt2 = 0; qt2 < 2; qt2++)
        #pragma unroll
        for (int i = 0; i < 4; i++) Oacc[qt2][i] = z16;
    float lsum[2] = {0.f, 0.f};        // per-lane partial rowsum (q=l31, this h's keys)

    // loop-invariant LDS read offsets
    int gl = (l31 & 3) ^ ((l31 >> 2) & 3);
    const unsigned short* kf0p0 = lK0 + (kh * 32 + l31) * 32 + ((0 + h) ^ gl) * 8;
    const unsigned short* kf1p0 = lK0 + (kh * 32 + l31) * 32 + ((2 + h) ^ gl) * 8;
    const unsigned short* kf0p1 = lK1 + (kh * 32 + l31) * 32 + ((0 + h) ^ gl) * 8;
    const unsigned short* kf1p1 = lK1 + (kh * 32 + l31) * 32 + ((2 + h) ^ gl) * 8;
    int slotA = ((kh * 4 + 0 * 2 + h) ^ (ln & 7)) * 8;
    int slotB = ((kh * 4 + 1 * 2 + h) ^ (ln & 7)) * 8;

    auto stage = [&](int kn, unsigned short* sK, unsigned short* sV) {
        glds16(gK + (size_t)kn * 4096, sK);
        #pragma unroll
        for (int j = 0; j < 4; j++)
            glds16(gV + ((size_t)j * 8 << 12) + kn * 64, sV + j * 512);
    };

    auto compute = [&](const unsigned short* kf0p, const unsigned short* kf1p,
                       const unsigned short* lV) {
        bf16x8 kf0 = *(const bf16x8*)kf0p;
        bf16x8 kf1 = *(const bf16x8*)kf1p;
        // all 4 QK MFMAs up front (independent)
        f32x16 St0 = mfma32(kf0, qb0[0], minit);
        St0 = mfma32(kf1, qb1[0], St0);
        f32x16 St1 = mfma32(kf0, qb0[1], minit);
        St1 = mfma32(kf1, qb1[1], St1);
        // exp for q-tile 0 (St1's MFMAs cover part of St0's latency)
        u16x8 p00, p01;
        float s0 = 0.f;
        #pragma unroll
        for (int j = 0; j < 8; j++) {
            float e0 = __builtin_amdgcn_exp2f(St0[j]);
            float e1 = __builtin_amdgcn_exp2f(St0[8 + j]);
            s0 += e0 + e1;                      // rowsum in VALU (lane=q, regs=keys)
            p00[j] = f2bf(e0);
            p01[j] = f2bf(e1);
        }
        lsum[0] += s0;
        bf16x8 pa00 = __builtin_bit_cast(bf16x8, p00);
        bf16x8 pa01 = __builtin_bit_cast(bf16x8, p01);
        // PV of q-tile 0 interleaved (program order!) with exp of q-tile 1:
        // the exp2/cvt stream issues while the matrix pipe chews the PV MFMAs.
        u16x8 p10, p11;
        float s1 = 0.f;
        __builtin_amdgcn_s_setprio(1);
        #pragma unroll
        for (int nt = 0; nt < 4; nt++) {
            bf16x8 vf = *(const bf16x8*)(lV + (nt * 32 + l31) * 64 + slotA);
            Oacc[0][nt] = mfma32(pa00, vf, Oacc[0][nt]);
            float e0 = __builtin_amdgcn_exp2f(St1[nt]);
            float e1 = __builtin_amdgcn_exp2f(St1[8 + nt]);
            s1 += e0 + e1;
            p10[nt] = f2bf(e0);
            p11[nt] = f2bf(e1);
        }
        #pragma unroll
        for (int nt = 0; nt < 4; nt++) {
            bf16x8 vf = *(const bf16x8*)(lV + (nt * 32 + l31) * 64 + slotB);
            Oacc[0][nt] = mfma32(pa01, vf, Oacc[0][nt]);
            float e0 = __builtin_amdgcn_exp2f(St1[4 + nt]);
            float e1 = __builtin_amdgcn_exp2f(St1[12 + nt]);
            s1 += e0 + e1;
            p10[4 + nt] = f2bf(e0);
            p11[4 + nt] = f2bf(e1);
        }
        lsum[1] += s1;
        bf16x8 pa10 = __builtin_bit_cast(bf16x8, p10);
        bf16x8 pa11 = __builtin_bit_cast(bf16x8, p11);
        // PV of q-tile 1 (issue mostly stalls on matrix pipe; the other
        // co-resident wave fills the VALU meanwhile)
        #pragma unroll
        for (int nt = 0; nt < 4; nt++) {
            bf16x8 vf = *(const bf16x8*)(lV + (nt * 32 + l31) * 64 + slotA);
            Oacc[1][nt] = mfma32(pa10, vf, Oacc[1][nt]);
        }
        #pragma unroll
        for (int nt = 0; nt < 4; nt++) {
            bf16x8 vf = *(const bf16x8*)(lV + (nt * 32 + l31) * 64 + slotB);
            Oacc[1][nt] = mfma32(pa11, vf, Oacc[1][nt]);
        }
        __builtin_amdgcn_s_setprio(0);
    };

    stage(0, sK0, sV0);                 // preload tile 0 into buf0
    for (int kt = 0; kt < 64; kt += 2) {
        // --- even tile: compute buf0, prefetch kt+1 into buf1 ---
        wait_vm0();                     // drain buf0's loads (issued 1 iter ago)
        barrier_raw();
        stage(kt + 1, sK1, sV1);
        compute(kf0p0, kf1p0, lV0);
        // --- odd tile: compute buf1, prefetch kt+2 into buf0 ---
        wait_vm0();
        barrier_raw();
        if (kt + 2 < 64) stage(kt + 2, sK0, sV0);
        compute(kf0p1, kf1p1, lV1);
    }
    // finish rowsums: combine the two h-halves (lane l31 and l31+32 hold
    // complementary key subsets for the same q)
    #pragma unroll
    for (int qt2 = 0; qt2 < 2; qt2++) lsum[qt2] += __shfl_xor(lsum[qt2], 32);
    __syncthreads();                    // all LDS reads done before smem reuse

    // ---- epilogue via smem reuse ----
    float* sf = (float*)smem;
    // lsum publish: [8192 + qh*64 + qt2*32 + q] (kh1), [8320 + ...] (kh0)
    int lbase = (kh ? 8192 : 8320) + qh * 64 + l31;
    sf[lbase] = lsum[0];
    sf[lbase + 32] = lsum[1];
    if (kh == 1) {                      // publish O partials (bf16)
        #pragma unroll
        for (int qt2 = 0; qt2 < 2; qt2++)
            #pragma unroll
            for (int nt = 0; nt < 4; nt++)
                #pragma unroll
                for (int rg = 0; rg < 2; rg++) {
                    u16x8 pk;
                    #pragma unroll
                    for (int j = 0; j < 8; j++) pk[j] = f2bf(Oacc[qt2][nt][rg * 8 + j]);
                    *(u16x8*)(smem + qh * 16384 + qt2 * 8192 + nt * 2048 + rg * 1024 + ln * 16) = pk;
                }
    }
    __syncthreads();
    if (kh == 0) {                      // reduce + normalize + store
        #pragma unroll
        for (int qt2 = 0; qt2 < 2; qt2++) {
            float rl[16];
            #pragma unroll
            for (int r = 0; r < 16; r++) {
                int row = (r & 3) + 8 * (r >> 2) + 4 * h;
                float l = sf[8192 + qh * 64 + qt2 * 32 + row] +
                          sf[8320 + qh * 64 + qt2 * 32 + row];
                rl[r] = 1.f / l;
            }
            size_t rb = (size_t)(b * 4096 + qblk * 128 + qh * 64 + qt2 * 32);
            #pragma unroll
            for (int nt = 0; nt < 4; nt++)
                #pragma unroll
                for (int rg = 0; rg < 2; rg++) {
                    u16x8 pk = *(const u16x8*)(smem + qh * 16384 + qt2 * 8192 + nt * 2048 + rg * 1024 + ln * 16);
                    #pragma unroll
                    for (int j = 0; j < 8; j++) {
                        int r = rg * 8 + j;
                        float val = (Oacc[qt2][nt][r] + bf2f(pk[j])) * rl[r];
                        int row = (r & 3) + 8 * (r >> 2) + 4 * h;
                        Oa[(rb + row) * 256 + oh * 128 + nt * 32 + l31] = f2bf(val);
                    }
                }
        }
    }
}

// ---------------- launch ----------------
extern "C" void kernel_launch(void* const* d_in, const int* in_sizes, int n_in,
                              void* d_out, int out_size, void* d_ws, size_t ws_size,
                              hipStream_t stream) {
    const float* x  = (const float*)d_in[0];
    const float* nw = (const float*)d_in[1];
    const float* nb = (const float*)d_in[2];
    const float* wq = (const float*)d_in[3];
    const float* wk = (const float*)d_in[4];
    const float* wv = (const float*)d_in[5];
    const float* wp = (const float*)d_in[6];
    const float* gm = (const float*)d_in[7];

    char* p = (char*)d_ws;
    unsigned short* ht  = (unsigned short*)p; p += (size_t)32768 * 256 * 2;  // 16 MB
    unsigned short* qk  = (unsigned short*)p; p += (size_t)32768 * 64 * 2;   // 4 MB
    unsigned short* vt  = (unsigned short*)p; p += (size_t)8 * 256 * 4096 * 2; // 16 MB
    unsigned short* oa  = (unsigned short*)p; p += (size_t)32768 * 256 * 2;  // 16 MB
    unsigned short* bqk = (unsigned short*)p; p += 64 * 256 * 2;
    unsigned short* bv  = (unsigned short*)p; p += 256 * 256 * 2;
    unsigned short* bp  = (unsigned short*)p; p += 256 * 256 * 2;

    k_pack<<<dim3(256), dim3(256), 0, stream>>>(wq, wk, wv, wp, bqk, bv, bp);
    k_gnorm<<<dim3(256), dim3(1024), 0, stream>>>(x, nw, nb, ht);
    // merged QK-proj (y=0) + V-proj (y=1..4)
    k_gemm<3><<<dim3(256, 5), dim3(256), 0, stream>>>(ht, bqk, (void*)qk, nullptr, nullptr, 64, bv, (void*)vt);
    k_flash<<<dim3(512), dim3(256), 0, stream>>>(qk, vt, oa);
    k_gemm<2><<<dim3(256, 4), dim3(256), 0, stream>>>(oa, bp, d_out, x, gm, 0, nullptr, nullptr);
}

// Round 5
// 225.308 us; speedup vs baseline: 4.0186x; 1.1937x over previous
//
#include <hip/hip_runtime.h>
#include <cstdint>

// Shapes: B=8, C=256, H=W=64 -> N=4096, d=32, groups=32 (8 ch/group)

typedef __bf16 bf16x8 __attribute__((ext_vector_type(8)));
typedef float f32x4 __attribute__((ext_vector_type(4)));
typedef float f32x16 __attribute__((ext_vector_type(16)));
typedef unsigned int u32x4 __attribute__((ext_vector_type(4)));
typedef unsigned short u16x4 __attribute__((ext_vector_type(4)));
typedef unsigned short u16x8 __attribute__((ext_vector_type(8)));

#define DEVI __device__ __forceinline__

DEVI unsigned short f2bf(float f) {
    __bf16 h = (__bf16)f;               // RNE fptrunc
    return __builtin_bit_cast(unsigned short, h);
}
DEVI float bf2f(unsigned short u) {
    unsigned int x = ((unsigned int)u) << 16;
    return __builtin_bit_cast(float, x);
}

DEVI f32x4 mfma16(bf16x8 a, bf16x8 b, f32x4 c) {
    return __builtin_amdgcn_mfma_f32_16x16x32_bf16(a, b, c, 0, 0, 0);
}
DEVI f32x16 mfma32(bf16x8 a, bf16x8 b, f32x16 c) {
    return __builtin_amdgcn_mfma_f32_32x32x16_bf16(a, b, c, 0, 0, 0);
}

// async global->LDS, 16B per lane, wave-uniform LDS base + lane*16
DEVI void glds16(const unsigned short* g, unsigned short* l) {
    const __attribute__((address_space(1))) unsigned int* gp =
        reinterpret_cast<const __attribute__((address_space(1))) unsigned int*>(
            reinterpret_cast<uintptr_t>(g));
    __attribute__((address_space(3))) unsigned int* lp =
        reinterpret_cast<__attribute__((address_space(3))) unsigned int*>(
            reinterpret_cast<uintptr_t>(l));
    __builtin_amdgcn_global_load_lds(gp, lp, 16, 0, 0);
}

// raw barrier without the compiler's vmcnt(0)-drain; manual waits only
DEVI void barrier_raw() {
    asm volatile("" ::: "memory");
    __builtin_amdgcn_s_barrier();
    asm volatile("" ::: "memory");
}
DEVI void wait_vm0() {
    // SIMM16: vmcnt[3:0]=0, expcnt[6:4]=7, lgkmcnt[13:8]=0x3F, vmcnt[5:4]=0
    __builtin_amdgcn_s_waitcnt(0x3F70);
}

// log2(e)/sqrt(32): folded into Wq so S exits QK-MFMA in exp2 domain
#define QSCALE 0.2550663133f
#define MFIX   12.0f

// ---------------- weight pack fp32 -> bf16 ----------------
__global__ __launch_bounds__(256) void k_pack(
        const float* __restrict__ wq, const float* __restrict__ wk,
        const float* __restrict__ wv, const float* __restrict__ wp,
        unsigned short* __restrict__ bqk, unsigned short* __restrict__ bv,
        unsigned short* __restrict__ bp) {
    int i = blockIdx.x * 256 + threadIdx.x;        // grid 256 -> 65536 threads
    if (i < 8192)       bqk[i] = f2bf(wq[i] * QSCALE);   // rows 0..31 = Wq (pre-scaled)
    else if (i < 16384) bqk[i] = f2bf(wk[i - 8192]);     // rows 32..63 = Wk
    bv[i] = f2bf(wv[i]);
    bp[i] = f2bf(wp[i]);
}

// ---------------- group norm -> h^T (B*N, C) bf16 ----------------
// Single-read version (round-5): the reduction pass and the normalize pass
// read EXACTLY the same 32 floats per thread (pass-1 f32x4 index t+1024k ==
// float 4t+4096k == cv[c] layout). Load cv[8] once (32 VGPRs across the
// reduction, ~60 total -> still full occupancy), sum from registers in the
// identical per-thread order (bitwise-same result), normalize from registers.
// Saves a full 64 MB HBM read (~10 us).
__global__ __launch_bounds__(1024) void k_gnorm(
        const float* __restrict__ x, const float* __restrict__ gw,
        const float* __restrict__ gb, unsigned short* __restrict__ ht) {
    int bg = blockIdx.x;               // 256 blocks = 8 batches * 32 groups
    int b = bg >> 5, g = bg & 31;
    const float* xb = x + ((size_t)(b * 256 + g * 8)) * 4096;  // 8 contiguous rows
    int t = threadIdx.x;
    int n0 = t * 4;
    f32x4 cv[8];
    #pragma unroll
    for (int c = 0; c < 8; c++) cv[c] = *(const f32x4*)(xb + c * 4096 + n0);
    float s1 = 0.f, s2 = 0.f;
    #pragma unroll
    for (int c = 0; c < 8; c++) {
        #pragma unroll
        for (int j = 0; j < 4; j++) { s1 += cv[c][j]; s2 += cv[c][j] * cv[c][j]; }
    }
    #pragma unroll
    for (int off = 1; off < 64; off <<= 1) {
        s1 += __shfl_xor(s1, off);
        s2 += __shfl_xor(s2, off);
    }
    __shared__ float red[34];
    int wv_ = t >> 6;
    if ((t & 63) == 0) { red[wv_ * 2] = s1; red[wv_ * 2 + 1] = s2; }
    __syncthreads();
    if (t == 0) {
        float a = 0.f, q = 0.f;
        #pragma unroll
        for (int i = 0; i < 16; i++) { a += red[i * 2]; q += red[i * 2 + 1]; }
        float mean = a * (1.f / 32768.f);
        float var = q * (1.f / 32768.f) - mean * mean;
        red[32] = mean; red[33] = rsqrtf(var + 1e-5f);
    }
    __syncthreads();
    float mean = red[32], rstd = red[33];
    float wv8[8], bv8[8];
    #pragma unroll
    for (int c = 0; c < 8; c++) { wv8[c] = gw[g * 8 + c] * rstd; bv8[c] = gb[g * 8 + c] - mean * rstd * gw[g * 8 + c]; }
    #pragma unroll
    for (int j = 0; j < 4; j++) {
        u16x8 pk;
        #pragma unroll
        for (int c = 0; c < 8; c++) pk[c] = f2bf(cv[c][j] * wv8[c] + bv8[c]);
        *(u16x8*)(&ht[((size_t)(b * 4096 + n0 + j)) * 256 + g * 8]) = pk;  // 16B store
    }
}

// ---------------- GEMM  C[M x Ncols] = A[M x 256] * Bw[Ncols x 256]^T ----------------
// EPI 0: bf16 row-major out (ldout).  EPI 1: bf16 transposed Vt[b][o][n] with
//        key-dim bit2<->bit3 swap per 16-group (PV A-frag permutation).
// EPI 2: fp32 transposed + residual: out[b][o][n] = x + gamma*acc.
// EPI 3: merged QK+V projection — y==0: EPI0 path (Bw -> outp, ldout);
//        y>=1: EPI1 path (Bw2 -> outp2, n0=(y-1)*64). Saves one full read of A
//        (16 MB) and one kernel launch vs separate <0>/<1> dispatches
//        (measured: non-flash 138.0 -> 126.7 us).
// Grid is the 2D form (x: m-panels, y: n-blocks). Round-1/2 evidence: per-XCD
// A-slice is L2-resident across y-slices already; 1D XCD swizzle was ~6us SLOWER.
template <int EPI>
__global__ __launch_bounds__(256) void k_gemm(
        const unsigned short* __restrict__ A, const unsigned short* __restrict__ Bw,
        void* __restrict__ outp, const float* __restrict__ xres,
        const float* __restrict__ gamma, int ldout,
        const unsigned short* __restrict__ Bw2, void* __restrict__ outp2) {
    __shared__ unsigned short lA[128 * 72];
    __shared__ unsigned short lB[64 * 72];
    int t = threadIdx.x;
    int m0 = blockIdx.x * 128, n0 = blockIdx.y * 64;
    const unsigned short* Bsrc = Bw;
    if (EPI == 3) {
        if (blockIdx.y == 0) { n0 = 0; }
        else { Bsrc = Bw2; n0 = (blockIdx.y - 1) * 64; }
    }
    int w = t >> 6, lane = t & 63, l15 = lane & 15, quad = lane >> 4;
    f32x4 z4 = {0.f, 0.f, 0.f, 0.f};
    f32x4 acc[2][4];
    #pragma unroll
    for (int i = 0; i < 2; i++)
        #pragma unroll
        for (int j = 0; j < 4; j++) acc[i][j] = z4;

    for (int kb = 0; kb < 4; kb++) {
        #pragma unroll
        for (int i = 0; i < 4; i++) {
            int ch = i * 256 + t;
            int row = ch >> 3, col = (ch & 7) * 8;
            u32x4 v = *(const u32x4*)(A + (size_t)(m0 + row) * 256 + kb * 64 + col);
            *(u32x4*)(&lA[row * 72 + col]) = v;
        }
        #pragma unroll
        for (int i = 0; i < 2; i++) {
            int ch = i * 256 + t;
            int row = ch >> 3, col = (ch & 7) * 8;
            u32x4 v = *(const u32x4*)(Bsrc + (size_t)(n0 + row) * 256 + kb * 64 + col);
            *(u32x4*)(&lB[row * 72 + col]) = v;
        }
        __syncthreads();
        #pragma unroll
        for (int ks = 0; ks < 2; ks++) {
            bf16x8 af[2], bfr[4];
            #pragma unroll
            for (int fr = 0; fr < 2; fr++)
                af[fr] = *(const bf16x8*)(&lA[(w * 32 + fr * 16 + l15) * 72 + ks * 32 + quad * 8]);
            #pragma unroll
            for (int fn = 0; fn < 4; fn++)
                bfr[fn] = *(const bf16x8*)(&lB[(fn * 16 + l15) * 72 + ks * 32 + quad * 8]);
            #pragma unroll
            for (int fr = 0; fr < 2; fr++)
                #pragma unroll
                for (int fn = 0; fn < 4; fn++)
                    acc[fr][fn] = mfma16(af[fr], bfr[fn], acc[fr][fn]);
        }
        __syncthreads();
    }

    bool epi0 = (EPI == 0) || (EPI == 3 && blockIdx.y == 0);
    bool epi1 = (EPI == 1) || (EPI == 3 && blockIdx.y != 0);
    if (epi0) {
        unsigned short* out = (unsigned short*)outp;
        #pragma unroll
        for (int fr = 0; fr < 2; fr++)
            #pragma unroll
            for (int fn = 0; fn < 4; fn++)
                #pragma unroll
                for (int r = 0; r < 4; r++) {
                    int m = m0 + w * 32 + fr * 16 + quad * 4 + r;
                    int n = n0 + fn * 16 + l15;
                    out[(size_t)m * ldout + n] = f2bf(acc[fr][fn][r]);
                }
    } else if (epi1) {
        unsigned short* out = (unsigned short*)((EPI == 3) ? outp2 : outp);
        int b = m0 >> 12, nb = (m0 & 4095) + w * 32;
        int swq = ((quad & 1) << 1) | (quad >> 1);   // bit2<->bit3 swap of n within 16
        #pragma unroll
        for (int fr = 0; fr < 2; fr++)
            #pragma unroll
            for (int fn = 0; fn < 4; fn++) {
                int o = n0 + fn * 16 + l15;
                int n = nb + fr * 16 + swq * 4;
                u16x4 pk;
                #pragma unroll
                for (int r = 0; r < 4; r++) pk[r] = f2bf(acc[fr][fn][r]);
                *(u16x4*)(&out[(((size_t)(b * 256 + o)) << 12) + n]) = pk;
            }
    } else {
        float* out = (float*)outp;
        float gm = gamma[0];
        int b = m0 >> 12, nb = (m0 & 4095) + w * 32;
        #pragma unroll
        for (int fr = 0; fr < 2; fr++)
            #pragma unroll
            for (int fn = 0; fn < 4; fn++) {
                int o = n0 + fn * 16 + l15;
                int n = nb + fr * 16 + quad * 4;
                size_t base = (((size_t)(b * 256 + o)) << 12) + n;
                f32x4 xv = *(const f32x4*)(xres + base);
                f32x4 ov;
                #pragma unroll
                for (int r = 0; r < 4; r++) ov[r] = xv[r] + gm * acc[fr][fn][r];
                *(f32x4*)(out + base) = ov;
            }
    }
}

// ---------------- flash attention: 32x32 MFMA, dbuf, q x2 reg-block, o-split,
//                  VALU rowsum, 2 blocks/CU ----------------
// QK: (B*N, 64) bf16 (q cols 0..31 pre-scaled, k cols 32..63).
// Vt: (B, 256, N) bf16, key-dim sigma-permuted (bit2<->bit3 per 16-group).
// Grid 512 = 8 b x 32 qblk(128q) x 2 oh(128 o-chans). 4 waves = 2 qh x 2 kh.
//
// REGISTER LEDGER (confirmed in rounds 1, 3, 4 — three spills): Oacc(128 acc)
// + ~128 arch = 256 VGPR cap exactly, ZERO headroom. Any change that raises
// peak liveness by even 16 regs (second pa set, St0+St1 both live, Q-in-LDS
// transients) spills to scratch: WRITE_SIZE explodes and the kernel goes
// HBM-bound on its own spills. The per-qt2 QK->exp then all-PV ordering below
// is the register-OPTIMAL ordering; do not reorder. This structure's measured
// optimum is ~99 us (MfmaUtil 38, VALUBusy 34).
__global__ __launch_bounds__(256, 2) void k_flash(
        const unsigned short* __restrict__ QK, const unsigned short* __restrict__ Vt,
        unsigned short* __restrict__ Oa) {
    __shared__ __align__(16) char smem[40960];   // dbuf 2 x (4KB K + 16KB V); epilogue reuse
    int id = blockIdx.x;
    int b = id & 7;                    // batch <-> XCD affinity
    int r3 = id >> 3;
    int oh = r3 & 1, qblk = r3 >> 1;   // o-half, q-block(128)
    int t = threadIdx.x, w = t >> 6, ln = t & 63;
    int l31 = ln & 31, h = ln >> 5;
    int qh = w >> 1, kh = w & 1;
    int q0 = qblk * 128 + qh * 64;     // this wave's 64-q range (2 tiles of 32)

    // persistent Q B-frags: B[k=d][n=q]; lane: q=l31, d = s*16 + h*8 + j
    bf16x8 qb0[2], qb1[2];
    #pragma unroll
    for (int qt2 = 0; qt2 < 2; qt2++) {
        const unsigned short* qrow = QK + ((size_t)(b * 4096 + q0 + qt2 * 32 + l31)) * 64;
        qb0[qt2] = *(const bf16x8*)(qrow + h * 8);
        qb1[qt2] = *(const bf16x8*)(qrow + 16 + h * 8);
    }

    // staging: K tile (wave w stages keys w*16..+16), chunk-swizzled for A-frag reads
    int cgK = (ln & 3) ^ ((ln >> 2) & 3) ^ ((ln >> 4) & 3);
    const unsigned short* gK = QK + ((size_t)(b * 4096 + w * 16 + (ln >> 2))) * 64 + 32 + cgK * 8;
    // V half-tile: wave w stages o-rows oh*128 + w*32..+32, chunk-swizzled
    int vc8 = (ln & 7) ^ ((ln >> 3) & 7);
    const unsigned short* gV = Vt + (((size_t)(b * 256 + oh * 128 + w * 32 + (ln >> 3))) << 12) + vc8 * 8;

    // double buffers: K 4KB + V 16KB each
    unsigned short* lK0 = (unsigned short*)smem;
    unsigned short* lV0 = (unsigned short*)(smem + 4096);
    unsigned short* lK1 = (unsigned short*)(smem + 20480);
    unsigned short* lV1 = (unsigned short*)(smem + 24576);
    unsigned short* sK0 = lK0 + w * 512;
    unsigned short* sV0 = lV0 + w * 2048;
    unsigned short* sK1 = lK1 + w * 512;
    unsigned short* sV1 = lV1 + w * 2048;

    f32x16 z16;
    #pragma unroll
    for (int i = 0; i < 16; i++) z16[i] = 0.f;
    f32x16 minit;
    #pragma unroll
    for (int i = 0; i < 16; i++) minit[i] = -MFIX;
    f32x16 Oacc[2][4];
    #pragma unroll
    for (int qt2 = 0; qt2 < 2; qt2++)
        #pragma unroll
        for (int i = 0; i < 4; i++) Oacc[qt2][i] = z16;
    float lsum[2] = {0.f, 0.f};        // per-lane partial rowsum (q=l31, this h's keys)

    // loop-invariant LDS read offsets
    int gl = (l31 & 3) ^ ((l31 >> 2) & 3);
    const unsigned short* kf0p0 = lK0 + (kh * 32 + l31) * 32 + ((0 + h) ^ gl) * 8;
    const unsigned short* kf1p0 = lK0 + (kh * 32 + l31) * 32 + ((2 + h) ^ gl) * 8;
    const unsigned short* kf0p1 = lK1 + (kh * 32 + l31) * 32 + ((0 + h) ^ gl) * 8;
    const unsigned short* kf1p1 = lK1 + (kh * 32 + l31) * 32 + ((2 + h) ^ gl) * 8;
    int slotA = ((kh * 4 + 0 * 2 + h) ^ (ln & 7)) * 8;
    int slotB = ((kh * 4 + 1 * 2 + h) ^ (ln & 7)) * 8;

    auto stage = [&](int kn, unsigned short* sK, unsigned short* sV) {
        glds16(gK + (size_t)kn * 4096, sK);
        #pragma unroll
        for (int j = 0; j < 4; j++)
            glds16(gV + ((size_t)j * 8 << 12) + kn * 64, sV + j * 512);
    };

    auto compute = [&](const unsigned short* kf0p, const unsigned short* kf1p,
                       const unsigned short* lV) {
        bf16x8 kf0 = *(const bf16x8*)kf0p;
        bf16x8 kf1 = *(const bf16x8*)kf1p;
        bf16x8 pa[2][2];
        #pragma unroll
        for (int qt2 = 0; qt2 < 2; qt2++) {
            f32x16 St = mfma32(kf0, qb0[qt2], minit);
            St = mfma32(kf1, qb1[qt2], St);
            u16x8 p0u, p1u;
            float s = 0.f;
            #pragma unroll
            for (int j = 0; j < 8; j++) {
                float e0 = __builtin_amdgcn_exp2f(St[j]);
                float e1 = __builtin_amdgcn_exp2f(St[8 + j]);
                s += e0 + e1;                       // rowsum in VALU (lane=q, regs=keys)
                p0u[j] = f2bf(e0);
                p1u[j] = f2bf(e1);
            }
            lsum[qt2] += s;
            pa[qt2][0] = __builtin_bit_cast(bf16x8, p0u);
            pa[qt2][1] = __builtin_bit_cast(bf16x8, p1u);
        }
        __builtin_amdgcn_s_setprio(1);
        #pragma unroll
        for (int nt = 0; nt < 4; nt++) {
            bf16x8 vf = *(const bf16x8*)(lV + (nt * 32 + l31) * 64 + slotA);
            Oacc[0][nt] = mfma32(pa[0][0], vf, Oacc[0][nt]);
            Oacc[1][nt] = mfma32(pa[1][0], vf, Oacc[1][nt]);
        }
        #pragma unroll
        for (int nt = 0; nt < 4; nt++) {
            bf16x8 vf = *(const bf16x8*)(lV + (nt * 32 + l31) * 64 + slotB);
            Oacc[0][nt] = mfma32(pa[0][1], vf, Oacc[0][nt]);
            Oacc[1][nt] = mfma32(pa[1][1], vf, Oacc[1][nt]);
        }
        __builtin_amdgcn_s_setprio(0);
    };

    stage(0, sK0, sV0);                 // preload tile 0 into buf0
    for (int kt = 0; kt < 64; kt += 2) {
        // --- even tile: compute buf0, prefetch kt+1 into buf1 ---
        wait_vm0();                     // drain buf0's loads (issued 1 iter ago)
        barrier_raw();
        stage(kt + 1, sK1, sV1);
        compute(kf0p0, kf1p0, lV0);
        // --- odd tile: compute buf1, prefetch kt+2 into buf0 ---
        wait_vm0();
        barrier_raw();
        if (kt + 2 < 64) stage(kt + 2, sK0, sV0);
        compute(kf0p1, kf1p1, lV1);
    }
    // finish rowsums: combine the two h-halves (lane l31 and l31+32 hold
    // complementary key subsets for the same q)
    #pragma unroll
    for (int qt2 = 0; qt2 < 2; qt2++) lsum[qt2] += __shfl_xor(lsum[qt2], 32);
    __syncthreads();                    // all LDS reads done before smem reuse

    // ---- epilogue via smem reuse ----
    float* sf = (float*)smem;
    // lsum publish: [8192 + qh*64 + qt2*32 + q] (kh1), [8320 + ...] (kh0)
    int lbase = (kh ? 8192 : 8320) + qh * 64 + l31;
    sf[lbase] = lsum[0];
    sf[lbase + 32] = lsum[1];
    if (kh == 1) {                      // publish O partials (bf16)
        #pragma unroll
        for (int qt2 = 0; qt2 < 2; qt2++)
            #pragma unroll
            for (int nt = 0; nt < 4; nt++)
                #pragma unroll
                for (int rg = 0; rg < 2; rg++) {
                    u16x8 pk;
                    #pragma unroll
                    for (int j = 0; j < 8; j++) pk[j] = f2bf(Oacc[qt2][nt][rg * 8 + j]);
                    *(u16x8*)(smem + qh * 16384 + qt2 * 8192 + nt * 2048 + rg * 1024 + ln * 16) = pk;
                }
    }
    __syncthreads();
    if (kh == 0) {                      // reduce + normalize + store
        #pragma unroll
        for (int qt2 = 0; qt2 < 2; qt2++) {
            float rl[16];
            #pragma unroll
            for (int r = 0; r < 16; r++) {
                int row = (r & 3) + 8 * (r >> 2) + 4 * h;
                float l = sf[8192 + qh * 64 + qt2 * 32 + row] +
                          sf[8320 + qh * 64 + qt2 * 32 + row];
                rl[r] = 1.f / l;
            }
            size_t rb = (size_t)(b * 4096 + qblk * 128 + qh * 64 + qt2 * 32);
            #pragma unroll
            for (int nt = 0; nt < 4; nt++)
                #pragma unroll
                for (int rg = 0; rg < 2; rg++) {
                    u16x8 pk = *(const u16x8*)(smem + qh * 16384 + qt2 * 8192 + nt * 2048 + rg * 1024 + ln * 16);
                    #pragma unroll
                    for (int j = 0; j < 8; j++) {
                        int r = rg * 8 + j;
                        float val = (Oacc[qt2][nt][r] + bf2f(pk[j])) * rl[r];
                        int row = (r & 3) + 8 * (r >> 2) + 4 * h;
                        Oa[(rb + row) * 256 + oh * 128 + nt * 32 + l31] = f2bf(val);
                    }
                }
        }
    }
}

// ---------------- launch ----------------
extern "C" void kernel_launch(void* const* d_in, const int* in_sizes, int n_in,
                              void* d_out, int out_size, void* d_ws, size_t ws_size,
                              hipStream_t stream) {
    const float* x  = (const float*)d_in[0];
    const float* nw = (const float*)d_in[1];
    const float* nb = (const float*)d_in[2];
    const float* wq = (const float*)d_in[3];
    const float* wk = (const float*)d_in[4];
    const float* wv = (const float*)d_in[5];
    const float* wp = (const float*)d_in[6];
    const float* gm = (const float*)d_in[7];

    char* p = (char*)d_ws;
    unsigned short* ht  = (unsigned short*)p; p += (size_t)32768 * 256 * 2;  // 16 MB
    unsigned short* qk  = (unsigned short*)p; p += (size_t)32768 * 64 * 2;   // 4 MB
    unsigned short* vt  = (unsigned short*)p; p += (size_t)8 * 256 * 4096 * 2; // 16 MB
    unsigned short* oa  = (unsigned short*)p; p += (size_t)32768 * 256 * 2;  // 16 MB
    unsigned short* bqk = (unsigned short*)p; p += 64 * 256 * 2;
    unsigned short* bv  = (unsigned short*)p; p += 256 * 256 * 2;
    unsigned short* bp  = (unsigned short*)p; p += 256 * 256 * 2;

    k_pack<<<dim3(256), dim3(256), 0, stream>>>(wq, wk, wv, wp, bqk, bv, bp);
    k_gnorm<<<dim3(256), dim3(1024), 0, stream>>>(x, nw, nb, ht);
    // merged QK-proj (y=0) + V-proj (y=1..4)
    k_gemm<3><<<dim3(256, 5), dim3(256), 0, stream>>>(ht, bqk, (void*)qk, nullptr, nullptr, 64, bv, (void*)vt);
    k_flash<<<dim3(512), dim3(256), 0, stream>>>(qk, vt, oa);
    k_gemm<2><<<dim3(256, 4), dim3(256), 0, stream>>>(oa, bp, d_out, x, gm, 0, nullptr, nullptr);
}

// Round 6
// 225.251 us; speedup vs baseline: 4.0196x; 1.0003x over previous
//
#include <hip/hip_runtime.h>
#include <cstdint>

// Shapes: B=8, C=256, H=W=64 -> N=4096, d=32, groups=32 (8 ch/group)

typedef __bf16 bf16x8 __attribute__((ext_vector_type(8)));
typedef float f32x4 __attribute__((ext_vector_type(4)));
typedef float f32x16 __attribute__((ext_vector_type(16)));
typedef unsigned int u32x4 __attribute__((ext_vector_type(4)));
typedef unsigned short u16x4 __attribute__((ext_vector_type(4)));
typedef unsigned short u16x8 __attribute__((ext_vector_type(8)));

#define DEVI __device__ __forceinline__

DEVI unsigned short f2bf(float f) {
    __bf16 h = (__bf16)f;               // RNE fptrunc
    return __builtin_bit_cast(unsigned short, h);
}
DEVI float bf2f(unsigned short u) {
    unsigned int x = ((unsigned int)u) << 16;
    return __builtin_bit_cast(float, x);
}

DEVI f32x4 mfma16(bf16x8 a, bf16x8 b, f32x4 c) {
    return __builtin_amdgcn_mfma_f32_16x16x32_bf16(a, b, c, 0, 0, 0);
}
DEVI f32x16 mfma32(bf16x8 a, bf16x8 b, f32x16 c) {
    return __builtin_amdgcn_mfma_f32_32x32x16_bf16(a, b, c, 0, 0, 0);
}

// async global->LDS, 16B per lane, wave-uniform LDS base + lane*16
DEVI void glds16(const unsigned short* g, unsigned short* l) {
    const __attribute__((address_space(1))) unsigned int* gp =
        reinterpret_cast<const __attribute__((address_space(1))) unsigned int*>(
            reinterpret_cast<uintptr_t>(g));
    __attribute__((address_space(3))) unsigned int* lp =
        reinterpret_cast<__attribute__((address_space(3))) unsigned int*>(
            reinterpret_cast<uintptr_t>(l));
    __builtin_amdgcn_global_load_lds(gp, lp, 16, 0, 0);
}

// raw barrier without the compiler's vmcnt(0)-drain; manual waits only
DEVI void barrier_raw() {
    asm volatile("" ::: "memory");
    __builtin_amdgcn_s_barrier();
    asm volatile("" ::: "memory");
}
DEVI void wait_vm0() {
    // SIMM16: vmcnt[3:0]=0, expcnt[6:4]=7, lgkmcnt[13:8]=0x3F, vmcnt[5:4]=0
    __builtin_amdgcn_s_waitcnt(0x3F70);
}

// log2(e)/sqrt(32): folded into Wq so S exits QK-MFMA in exp2 domain
#define QSCALE 0.2550663133f
#define MFIX   12.0f

// ---------------- group norm -> h^T (B*N, C) bf16 ----------------
// Single-read: reduction and normalize passes use the same cv[8] registers
// (32 VGPRs across the reduction; bitwise-identical per-thread sum order).
__global__ __launch_bounds__(1024) void k_gnorm(
        const float* __restrict__ x, const float* __restrict__ gw,
        const float* __restrict__ gb, unsigned short* __restrict__ ht) {
    int bg = blockIdx.x;               // 256 blocks = 8 batches * 32 groups
    int b = bg >> 5, g = bg & 31;
    const float* xb = x + ((size_t)(b * 256 + g * 8)) * 4096;  // 8 contiguous rows
    int t = threadIdx.x;
    int n0 = t * 4;
    f32x4 cv[8];
    #pragma unroll
    for (int c = 0; c < 8; c++) cv[c] = *(const f32x4*)(xb + c * 4096 + n0);
    float s1 = 0.f, s2 = 0.f;
    #pragma unroll
    for (int c = 0; c < 8; c++) {
        #pragma unroll
        for (int j = 0; j < 4; j++) { s1 += cv[c][j]; s2 += cv[c][j] * cv[c][j]; }
    }
    #pragma unroll
    for (int off = 1; off < 64; off <<= 1) {
        s1 += __shfl_xor(s1, off);
        s2 += __shfl_xor(s2, off);
    }
    __shared__ float red[34];
    int wv_ = t >> 6;
    if ((t & 63) == 0) { red[wv_ * 2] = s1; red[wv_ * 2 + 1] = s2; }
    __syncthreads();
    if (t == 0) {
        float a = 0.f, q = 0.f;
        #pragma unroll
        for (int i = 0; i < 16; i++) { a += red[i * 2]; q += red[i * 2 + 1]; }
        float mean = a * (1.f / 32768.f);
        float var = q * (1.f / 32768.f) - mean * mean;
        red[32] = mean; red[33] = rsqrtf(var + 1e-5f);
    }
    __syncthreads();
    float mean = red[32], rstd = red[33];
    float wv8[8], bv8[8];
    #pragma unroll
    for (int c = 0; c < 8; c++) { wv8[c] = gw[g * 8 + c] * rstd; bv8[c] = gb[g * 8 + c] - mean * rstd * gw[g * 8 + c]; }
    #pragma unroll
    for (int j = 0; j < 4; j++) {
        u16x8 pk;
        #pragma unroll
        for (int c = 0; c < 8; c++) pk[c] = f2bf(cv[c][j] * wv8[c] + bv8[c]);
        *(u16x8*)(&ht[((size_t)(b * 4096 + n0 + j)) * 256 + g * 8]) = pk;  // 16B store
    }
}

// ---------------- GEMM  C[M x Ncols] = A[M x 256] * W[Ncols x 256]^T ----------------
// Weights are read as fp32 and converted to bf16 DURING B-staging (replaces
// the old k_pack dispatch; bit-identical f2bf RNE sequence, weights are
// KB-scale and cache-resident so the wider reads are free).
// EPI 2: fp32 transposed + residual: out[b][o][n] = x + gamma*acc.  W = Wproj.
// EPI 3: merged QK+V projection — y==0: Wq(x QSCALE, rows 0..31)+Wk(rows
//        32..63) -> qk row-major (ldout=64); y>=1: Wv -> Vt[b][o][n] bf16
//        transposed with key-dim bit2<->bit3 swap (n0=(y-1)*64).
// Grid 2D (x: m-panels, y: n-blocks); 1D XCD swizzle measured SLOWER (round 1).
template <int EPI>
__global__ __launch_bounds__(256) void k_gemm(
        const unsigned short* __restrict__ A, void* __restrict__ outp,
        const float* __restrict__ xres, const float* __restrict__ gamma, int ldout,
        const float* __restrict__ wqf, const float* __restrict__ wkf,
        const float* __restrict__ wvf, void* __restrict__ outp2) {
    __shared__ unsigned short lA[128 * 72];
    __shared__ unsigned short lB[64 * 72];
    int t = threadIdx.x;
    int m0 = blockIdx.x * 128, n0 = blockIdx.y * 64;
    if (EPI == 3) {
        if (blockIdx.y == 0) n0 = 0;
        else n0 = (blockIdx.y - 1) * 64;
    }
    int w = t >> 6, lane = t & 63, l15 = lane & 15, quad = lane >> 4;
    f32x4 z4 = {0.f, 0.f, 0.f, 0.f};
    f32x4 acc[2][4];
    #pragma unroll
    for (int i = 0; i < 2; i++)
        #pragma unroll
        for (int j = 0; j < 4; j++) acc[i][j] = z4;

    // fp32 weight row fetch + convert: 8 bf16 for (tile row, global col gc)
    auto ldB8 = [&](int row, int gc) -> u16x8 {
        const float* src;
        float sc = 1.f;
        if (EPI == 3) {
            if (blockIdx.y == 0) {
                if (row < 32) { src = wqf + (size_t)row * 256 + gc; sc = QSCALE; }
                else          { src = wkf + (size_t)(row - 32) * 256 + gc; }
            } else {
                src = wvf + (size_t)(n0 + row) * 256 + gc;
            }
        } else {
            src = wvf + (size_t)(n0 + row) * 256 + gc;   // EPI2: wvf = Wproj
        }
        f32x4 a = *(const f32x4*)src;
        f32x4 b2 = *(const f32x4*)(src + 4);
        u16x8 r;
        #pragma unroll
        for (int j = 0; j < 4; j++) { r[j] = f2bf(a[j] * sc); r[4 + j] = f2bf(b2[j] * sc); }
        return r;
    };

    for (int kb = 0; kb < 4; kb++) {
        #pragma unroll
        for (int i = 0; i < 4; i++) {
            int ch = i * 256 + t;
            int row = ch >> 3, col = (ch & 7) * 8;
            u32x4 v = *(const u32x4*)(A + (size_t)(m0 + row) * 256 + kb * 64 + col);
            *(u32x4*)(&lA[row * 72 + col]) = v;
        }
        #pragma unroll
        for (int i = 0; i < 2; i++) {
            int ch = i * 256 + t;
            int row = ch >> 3, col = (ch & 7) * 8;
            u16x8 v = ldB8(row, kb * 64 + col);
            *(u16x8*)(&lB[row * 72 + col]) = v;
        }
        __syncthreads();
        #pragma unroll
        for (int ks = 0; ks < 2; ks++) {
            bf16x8 af[2], bfr[4];
            #pragma unroll
            for (int fr = 0; fr < 2; fr++)
                af[fr] = *(const bf16x8*)(&lA[(w * 32 + fr * 16 + l15) * 72 + ks * 32 + quad * 8]);
            #pragma unroll
            for (int fn = 0; fn < 4; fn++)
                bfr[fn] = *(const bf16x8*)(&lB[(fn * 16 + l15) * 72 + ks * 32 + quad * 8]);
            #pragma unroll
            for (int fr = 0; fr < 2; fr++)
                #pragma unroll
                for (int fn = 0; fn < 4; fn++)
                    acc[fr][fn] = mfma16(af[fr], bfr[fn], acc[fr][fn]);
        }
        __syncthreads();
    }

    bool epi0 = (EPI == 3 && blockIdx.y == 0);
    bool epi1 = (EPI == 3 && blockIdx.y != 0);
    if (epi0) {
        unsigned short* out = (unsigned short*)outp;
        #pragma unroll
        for (int fr = 0; fr < 2; fr++)
            #pragma unroll
            for (int fn = 0; fn < 4; fn++)
                #pragma unroll
                for (int r = 0; r < 4; r++) {
                    int m = m0 + w * 32 + fr * 16 + quad * 4 + r;
                    int n = n0 + fn * 16 + l15;
                    out[(size_t)m * ldout + n] = f2bf(acc[fr][fn][r]);
                }
    } else if (epi1) {
        unsigned short* out = (unsigned short*)outp2;
        int b = m0 >> 12, nb = (m0 & 4095) + w * 32;
        int swq = ((quad & 1) << 1) | (quad >> 1);   // bit2<->bit3 swap of n within 16
        #pragma unroll
        for (int fr = 0; fr < 2; fr++)
            #pragma unroll
            for (int fn = 0; fn < 4; fn++) {
                int o = n0 + fn * 16 + l15;
                int n = nb + fr * 16 + swq * 4;
                u16x4 pk;
                #pragma unroll
                for (int r = 0; r < 4; r++) pk[r] = f2bf(acc[fr][fn][r]);
                *(u16x4*)(&out[(((size_t)(b * 256 + o)) << 12) + n]) = pk;
            }
    } else {
        float* out = (float*)outp;
        float gm = gamma[0];
        int b = m0 >> 12, nb = (m0 & 4095) + w * 32;
        #pragma unroll
        for (int fr = 0; fr < 2; fr++)
            #pragma unroll
            for (int fn = 0; fn < 4; fn++) {
                int o = n0 + fn * 16 + l15;
                int n = nb + fr * 16 + quad * 4;
                size_t base = (((size_t)(b * 256 + o)) << 12) + n;
                f32x4 xv = *(const f32x4*)(xres + base);
                f32x4 ov;
                #pragma unroll
                for (int r = 0; r < 4; r++) ov[r] = xv[r] + gm * acc[fr][fn][r];
                *(f32x4*)(out + base) = ov;
            }
    }
}

// ---------------- flash attention: 32x32 MFMA, dbuf, q x2 reg-block, o-split,
//                  VALU rowsum, 2 blocks/CU ----------------
// QK: (B*N, 64) bf16 (q cols 0..31 pre-scaled, k cols 32..63).
// Vt: (B, 256, N) bf16, key-dim sigma-permuted (bit2<->bit3 per 16-group).
// Grid 512 = 8 b x 32 qblk(128q) x 2 oh(128 o-chans). 4 waves = 2 qh x 2 kh.
//
// REGISTER LEDGER (confirmed in rounds 1, 3, 4 — three spills): Oacc(128 acc)
// + ~128 arch = 256 VGPR cap exactly, ZERO headroom. Any change that raises
// peak liveness by even 16 regs (second pa set, St0+St1 both live, Q-in-LDS
// transients) spills to scratch: WRITE_SIZE explodes and the kernel goes
// HBM-bound on its own spills. The per-qt2 QK->exp then all-PV ordering below
// is the register-OPTIMAL ordering; do not reorder. Measured optimum of this
// structure: 97.0 us (MfmaUtil 39.2, VALUBusy 35.3). FROZEN.
__global__ __launch_bounds__(256, 2) void k_flash(
        const unsigned short* __restrict__ QK, const unsigned short* __restrict__ Vt,
        unsigned short* __restrict__ Oa) {
    __shared__ __align__(16) char smem[40960];   // dbuf 2 x (4KB K + 16KB V); epilogue reuse
    int id = blockIdx.x;
    int b = id & 7;                    // batch <-> XCD affinity
    int r3 = id >> 3;
    int oh = r3 & 1, qblk = r3 >> 1;   // o-half, q-block(128)
    int t = threadIdx.x, w = t >> 6, ln = t & 63;
    int l31 = ln & 31, h = ln >> 5;
    int qh = w >> 1, kh = w & 1;
    int q0 = qblk * 128 + qh * 64;     // this wave's 64-q range (2 tiles of 32)

    // persistent Q B-frags: B[k=d][n=q]; lane: q=l31, d = s*16 + h*8 + j
    bf16x8 qb0[2], qb1[2];
    #pragma unroll
    for (int qt2 = 0; qt2 < 2; qt2++) {
        const unsigned short* qrow = QK + ((size_t)(b * 4096 + q0 + qt2 * 32 + l31)) * 64;
        qb0[qt2] = *(const bf16x8*)(qrow + h * 8);
        qb1[qt2] = *(const bf16x8*)(qrow + 16 + h * 8);
    }

    // staging: K tile (wave w stages keys w*16..+16), chunk-swizzled for A-frag reads
    int cgK = (ln & 3) ^ ((ln >> 2) & 3) ^ ((ln >> 4) & 3);
    const unsigned short* gK = QK + ((size_t)(b * 4096 + w * 16 + (ln >> 2))) * 64 + 32 + cgK * 8;
    // V half-tile: wave w stages o-rows oh*128 + w*32..+32, chunk-swizzled
    int vc8 = (ln & 7) ^ ((ln >> 3) & 7);
    const unsigned short* gV = Vt + (((size_t)(b * 256 + oh * 128 + w * 32 + (ln >> 3))) << 12) + vc8 * 8;

    // double buffers: K 4KB + V 16KB each
    unsigned short* lK0 = (unsigned short*)smem;
    unsigned short* lV0 = (unsigned short*)(smem + 4096);
    unsigned short* lK1 = (unsigned short*)(smem + 20480);
    unsigned short* lV1 = (unsigned short*)(smem + 24576);
    unsigned short* sK0 = lK0 + w * 512;
    unsigned short* sV0 = lV0 + w * 2048;
    unsigned short* sK1 = lK1 + w * 512;
    unsigned short* sV1 = lV1 + w * 2048;

    f32x16 z16;
    #pragma unroll
    for (int i = 0; i < 16; i++) z16[i] = 0.f;
    f32x16 minit;
    #pragma unroll
    for (int i = 0; i < 16; i++) minit[i] = -MFIX;
    f32x16 Oacc[2][4];
    #pragma unroll
    for (int qt2 = 0; qt2 < 2; qt2++)
        #pragma unroll
        for (int i = 0; i < 4; i++) Oacc[qt2][i] = z16;
    float lsum[2] = {0.f, 0.f};        // per-lane partial rowsum (q=l31, this h's keys)

    // loop-invariant LDS read offsets
    int gl = (l31 & 3) ^ ((l31 >> 2) & 3);
    const unsigned short* kf0p0 = lK0 + (kh * 32 + l31) * 32 + ((0 + h) ^ gl) * 8;
    const unsigned short* kf1p0 = lK0 + (kh * 32 + l31) * 32 + ((2 + h) ^ gl) * 8;
    const unsigned short* kf0p1 = lK1 + (kh * 32 + l31) * 32 + ((0 + h) ^ gl) * 8;
    const unsigned short* kf1p1 = lK1 + (kh * 32 + l31) * 32 + ((2 + h) ^ gl) * 8;
    int slotA = ((kh * 4 + 0 * 2 + h) ^ (ln & 7)) * 8;
    int slotB = ((kh * 4 + 1 * 2 + h) ^ (ln & 7)) * 8;

    auto stage = [&](int kn, unsigned short* sK, unsigned short* sV) {
        glds16(gK + (size_t)kn * 4096, sK);
        #pragma unroll
        for (int j = 0; j < 4; j++)
            glds16(gV + ((size_t)j * 8 << 12) + kn * 64, sV + j * 512);
    };

    auto compute = [&](const unsigned short* kf0p, const unsigned short* kf1p,
                       const unsigned short* lV) {
        bf16x8 kf0 = *(const bf16x8*)kf0p;
        bf16x8 kf1 = *(const bf16x8*)kf1p;
        bf16x8 pa[2][2];
        #pragma unroll
        for (int qt2 = 0; qt2 < 2; qt2++) {
            f32x16 St = mfma32(kf0, qb0[qt2], minit);
            St = mfma32(kf1, qb1[qt2], St);
            u16x8 p0u, p1u;
            float s = 0.f;
            #pragma unroll
            for (int j = 0; j < 8; j++) {
                float e0 = __builtin_amdgcn_exp2f(St[j]);
                float e1 = __builtin_amdgcn_exp2f(St[8 + j]);
                s += e0 + e1;                       // rowsum in VALU (lane=q, regs=keys)
                p0u[j] = f2bf(e0);
                p1u[j] = f2bf(e1);
            }
            lsum[qt2] += s;
            pa[qt2][0] = __builtin_bit_cast(bf16x8, p0u);
            pa[qt2][1] = __builtin_bit_cast(bf16x8, p1u);
        }
        __builtin_amdgcn_s_setprio(1);
        #pragma unroll
        for (int nt = 0; nt < 4; nt++) {
            bf16x8 vf = *(const bf16x8*)(lV + (nt * 32 + l31) * 64 + slotA);
            Oacc[0][nt] = mfma32(pa[0][0], vf, Oacc[0][nt]);
            Oacc[1][nt] = mfma32(pa[1][0], vf, Oacc[1][nt]);
        }
        #pragma unroll
        for (int nt = 0; nt < 4; nt++) {
            bf16x8 vf = *(const bf16x8*)(lV + (nt * 32 + l31) * 64 + slotB);
            Oacc[0][nt] = mfma32(pa[0][1], vf, Oacc[0][nt]);
            Oacc[1][nt] = mfma32(pa[1][1], vf, Oacc[1][nt]);
        }
        __builtin_amdgcn_s_setprio(0);
    };

    stage(0, sK0, sV0);                 // preload tile 0 into buf0
    for (int kt = 0; kt < 64; kt += 2) {
        // --- even tile: compute buf0, prefetch kt+1 into buf1 ---
        wait_vm0();                     // drain buf0's loads (issued 1 iter ago)
        barrier_raw();
        stage(kt + 1, sK1, sV1);
        compute(kf0p0, kf1p0, lV0);
        // --- odd tile: compute buf1, prefetch kt+2 into buf0 ---
        wait_vm0();
        barrier_raw();
        if (kt + 2 < 64) stage(kt + 2, sK0, sV0);
        compute(kf0p1, kf1p1, lV1);
    }
    // finish rowsums: combine the two h-halves (lane l31 and l31+32 hold
    // complementary key subsets for the same q)
    #pragma unroll
    for (int qt2 = 0; qt2 < 2; qt2++) lsum[qt2] += __shfl_xor(lsum[qt2], 32);
    __syncthreads();                    // all LDS reads done before smem reuse

    // ---- epilogue via smem reuse ----
    float* sf = (float*)smem;
    // lsum publish: [8192 + qh*64 + qt2*32 + q] (kh1), [8320 + ...] (kh0)
    int lbase = (kh ? 8192 : 8320) + qh * 64 + l31;
    sf[lbase] = lsum[0];
    sf[lbase + 32] = lsum[1];
    if (kh == 1) {                      // publish O partials (bf16)
        #pragma unroll
        for (int qt2 = 0; qt2 < 2; qt2++)
            #pragma unroll
            for (int nt = 0; nt < 4; nt++)
                #pragma unroll
                for (int rg = 0; rg < 2; rg++) {
                    u16x8 pk;
                    #pragma unroll
                    for (int j = 0; j < 8; j++) pk[j] = f2bf(Oacc[qt2][nt][rg * 8 + j]);
                    *(u16x8*)(smem + qh * 16384 + qt2 * 8192 + nt * 2048 + rg * 1024 + ln * 16) = pk;
                }
    }
    __syncthreads();
    if (kh == 0) {                      // reduce + normalize + store
        #pragma unroll
        for (int qt2 = 0; qt2 < 2; qt2++) {
            float rl[16];
            #pragma unroll
            for (int r = 0; r < 16; r++) {
                int row = (r & 3) + 8 * (r >> 2) + 4 * h;
                float l = sf[8192 + qh * 64 + qt2 * 32 + row] +
                          sf[8320 + qh * 64 + qt2 * 32 + row];
                rl[r] = 1.f / l;
            }
            size_t rb = (size_t)(b * 4096 + qblk * 128 + qh * 64 + qt2 * 32);
            #pragma unroll
            for (int nt = 0; nt < 4; nt++)
                #pragma unroll
                for (int rg = 0; rg < 2; rg++) {
                    u16x8 pk = *(const u16x8*)(smem + qh * 16384 + qt2 * 8192 + nt * 2048 + rg * 1024 + ln * 16);
                    #pragma unroll
                    for (int j = 0; j < 8; j++) {
                        int r = rg * 8 + j;
                        float val = (Oacc[qt2][nt][r] + bf2f(pk[j])) * rl[r];
                        int row = (r & 3) + 8 * (r >> 2) + 4 * h;
                        Oa[(rb + row) * 256 + oh * 128 + nt * 32 + l31] = f2bf(val);
                    }
                }
        }
    }
}

// ---------------- launch ----------------
extern "C" void kernel_launch(void* const* d_in, const int* in_sizes, int n_in,
                              void* d_out, int out_size, void* d_ws, size_t ws_size,
                              hipStream_t stream) {
    const float* x  = (const float*)d_in[0];
    const float* nw = (const float*)d_in[1];
    const float* nb = (const float*)d_in[2];
    const float* wq = (const float*)d_in[3];
    const float* wk = (const float*)d_in[4];
    const float* wv = (const float*)d_in[5];
    const float* wp = (const float*)d_in[6];
    const float* gm = (const float*)d_in[7];

    char* p = (char*)d_ws;
    unsigned short* ht  = (unsigned short*)p; p += (size_t)32768 * 256 * 2;  // 16 MB
    unsigned short* qk  = (unsigned short*)p; p += (size_t)32768 * 64 * 2;   // 4 MB
    unsigned short* vt  = (unsigned short*)p; p += (size_t)8 * 256 * 4096 * 2; // 16 MB
    unsigned short* oa  = (unsigned short*)p; p += (size_t)32768 * 256 * 2;  // 16 MB

    k_gnorm<<<dim3(256), dim3(1024), 0, stream>>>(x, nw, nb, ht);
    // merged QK-proj (y=0, Wq/Wk converted in-staging) + V-proj (y=1..4)
    k_gemm<3><<<dim3(256, 5), dim3(256), 0, stream>>>(ht, (void*)qk, nullptr, nullptr, 64, wq, wk, wv, (void*)vt);
    k_flash<<<dim3(512), dim3(256), 0, stream>>>(qk, vt, oa);
    // output projection + residual (Wproj converted in-staging)
    k_gemm<2><<<dim3(256, 4), dim3(256), 0, stream>>>(oa, d_out, x, gm, 0, nullptr, nullptr, wp, nullptr);
}